// Round 13
// baseline (2254.012 us; speedup 1.0000x reference)
//
#include <hip/hip_runtime.h>
#include <hip/hip_fp16.h>

typedef _Float16 f16;
typedef _Float16 f16x2 __attribute__((ext_vector_type(2)));
typedef _Float16 f16x4 __attribute__((ext_vector_type(4)));
typedef _Float16 f16x8 __attribute__((ext_vector_type(8)));
typedef float    f32x4 __attribute__((ext_vector_type(4)));
typedef unsigned long long u64t;

#define DEV __device__ __forceinline__

constexpr int B = 32, T = 64, S = 64, H = 512, E = 512, V = 32000;
constexpr int BT = B * T;      // 2048
constexpr int G4 = 4 * H;      // 2048
constexpr int NBLK = 64;       // scan blocks
constexpr int NFEED = 32;      // feeder blocks (1 per batch)
constexpr int NCONS = 152;     // logits consumer blocks

DEV float sigf(float x) { return 1.f / (1.f + expf(-x)); }

#if defined(__has_builtin)
#if __has_builtin(__builtin_amdgcn_global_load_lds)
#define HAVE_GLL 1
#endif
#if __has_builtin(__builtin_amdgcn_fdot2)
#define HAVE_FDOT2 1
#endif
#endif

DEV float dot2f(unsigned a, unsigned b, float c) {
#if HAVE_FDOT2
    return __builtin_amdgcn_fdot2(__builtin_bit_cast(f16x2, a),
                                  __builtin_bit_cast(f16x2, b), c, false);
#else
    f16x2 av = __builtin_bit_cast(f16x2, a);
    f16x2 bv = __builtin_bit_cast(f16x2, b);
    return c + (float)av.x * (float)bv.x + (float)av.y * (float)bv.y;
#endif
}

// relaxed agent-scope = plain sc1 loads/stores (MALL-coherent, no wbl2/inv)
DEV u64t ld_u64_cg(const u64t* p) {
    return __hip_atomic_load(p, __ATOMIC_RELAXED, __HIP_MEMORY_SCOPE_AGENT);
}
DEV unsigned ld_u32_cg(const unsigned* p) {
    return __hip_atomic_load(p, __ATOMIC_RELAXED, __HIP_MEMORY_SCOPE_AGENT);
}
DEV void st_u32_cg(unsigned* p, unsigned v) {
    __hip_atomic_store(p, v, __ATOMIC_RELAXED, __HIP_MEMORY_SCOPE_AGENT);
}

#if HAVE_GLL
DEV void gll16(f16* lds, const f16* g) {
    __builtin_amdgcn_global_load_lds(
        (const __attribute__((address_space(1))) void*)g,
        (__attribute__((address_space(3))) void*)lds, 16, 0, 0);
}
#endif

DEV unsigned pkh2(float a, float b) {
    f16x2 h = {(f16)a, (f16)b};
    return __builtin_bit_cast(unsigned, h);
}

// ---------------- converts / packing ----------------

__global__ __launch_bounds__(256) void cvt_f16(const float* __restrict__ s,
                                               f16* __restrict__ d, int n4) {
    for (int i = blockIdx.x * blockDim.x + threadIdx.x; i < n4;
         i += gridDim.x * blockDim.x) {
        float4 v = ((const float4*)s)[i];
        f16x4 o = {(f16)v.x, (f16)v.y, (f16)v.z, (f16)v.w};
        ((f16x4*)d)[i] = o;
    }
}

// Pack W_hh [2048][512] f32 into MFMA B-fragment order, f16 (R6 layout).
__global__ __launch_bounds__(256) void pack_wfrag(const float* __restrict__ W,
                                                  f16* __restrict__ Wf) {
    int id = blockIdx.x * 256 + threadIdx.x;  // 2^17 total
    if (id >= NBLK * 2 * 16 * 64) return;
    int lane = id & 63;
    int ks = (id >> 6) & 15;
    int ni = (id >> 10) & 1;
    int n = id >> 11;
    int cl = ni * 16 + (lane & 15);
    int ul = cl >> 2, g = cl & 3;
    int unit = n * 8 + ul;
    int k = ks * 32 + (lane >> 4) * 8;
    const float* src = W + (size_t)(g * 512 + unit) * 512 + k;
    float4 a = *(const float4*)src;
    float4 b = *(const float4*)(src + 4);
    f16x8 o = {(f16)a.x, (f16)a.y, (f16)a.z, (f16)a.w,
               (f16)b.x, (f16)b.y, (f16)b.z, (f16)b.w};
    *(f16x8*)(Wf + (size_t)id * 8) = o;
}

// wattP4 uint4[k8 (64)][j (1024)] : 4 packed f16-pairs of W_att[j][k8*8 ..+8)
__global__ __launch_bounds__(256) void pack_watt4(const float* __restrict__ W,
                                                  uint4* __restrict__ P) {
    int id = blockIdx.x * 256 + threadIdx.x;
    if (id >= 64 * 1024) return;
    int j = id & 1023, k8 = id >> 10;
    const float* src = W + (size_t)j * 512 + k8 * 8;
    float4 a = *(const float4*)src;
    float4 b = *(const float4*)(src + 4);
    uint4 o = {pkh2(a.x, a.y), pkh2(a.z, a.w), pkh2(b.x, b.y), pkh2(b.z, b.w)};
    P[(size_t)k8 * 1024 + j] = o;
}

// wcombP4 uint4[k8 (192)][j (512)] : pairs of W_comb[j][k8*8 ..+8)
__global__ __launch_bounds__(256) void pack_wcomb4(const float* __restrict__ W,
                                                   uint4* __restrict__ P) {
    int id = blockIdx.x * 256 + threadIdx.x;
    if (id >= 192 * 512) return;
    int j = id & 511, k8 = id >> 9;
    const float* src = W + (size_t)j * 1536 + k8 * 8;
    float4 a = *(const float4*)src;
    float4 b = *(const float4*)(src + 4);
    uint4 o = {pkh2(a.x, a.y), pkh2(a.z, a.w), pkh2(b.x, b.y), pkh2(b.z, b.w)};
    P[(size_t)k8 * 512 + j] = o;
}

// x[bt][e] = (f16) emb[tok[bt]][e]
__global__ __launch_bounds__(256) void gather_x(const int* __restrict__ tok,
                                                const float* __restrict__ emb,
                                                f16* __restrict__ x) {
    int id = blockIdx.x * blockDim.x + threadIdx.x;  // 2048*128
    if (id >= BT * (E / 4)) return;
    int row = id >> 7;
    int e4 = (id & 127) * 4;
    int t = tok[row];
    float4 v = *(const float4*)(emb + (size_t)t * E + e4);
    f16x4 o = {(f16)v.x, (f16)v.y, (f16)v.z, (f16)v.w};
    ((f16x4*)x)[id] = o;
}

// stage h0 into xbuf[0] (block-major) and reset flags/oflags (replay safe)
__global__ __launch_bounds__(256) void init_h0(const float* __restrict__ h0,
                                               f16* __restrict__ xbuf,
                                               unsigned* __restrict__ fl,
                                               unsigned* __restrict__ ofl) {
    int i = blockIdx.x * 256 + threadIdx.x;  // 64 blocks -> 16384
    if (i < B * H) {
        int nn = i >> 8;
        int bb = (i >> 3) & 31;
        int ul = i & 7;
        xbuf[i] = (f16)h0[bb * 512 + nn * 8 + ul];
    }
    if (i < NBLK) fl[i] = 0u;
    if (i < NFEED) ofl[i] = 0u;
}

// ---------------- gates GEMM (proven; PERM output layout) ----------------

template <bool BIAS, bool B2, bool PERM, typename OUT>
__global__ __launch_bounds__(256) void gemm_bt(
    const f16* __restrict__ A, int lda, const f16* __restrict__ W, int ldw,
    OUT* __restrict__ C, int ldc, int K, const float* __restrict__ bias1,
    const float* __restrict__ bias2) {
    __shared__ f16 smA[128 * 32];
    __shared__ f16 smB[128 * 32];
    const int tid = threadIdx.x;
    const int lane = tid & 63;
    const int wv = tid >> 6;
    const int wr = wv >> 1, wc = wv & 1;
    const int m0 = blockIdx.y * 128, n0 = blockIdx.x * 128;
    const int ar0 = tid >> 2;
    const int kq = (tid & 3) * 8;

    f32x4 acc[4][4];
#pragma unroll
    for (int m = 0; m < 4; m++)
#pragma unroll
        for (int n = 0; n < 4; n++) acc[m][n] = {0.f, 0.f, 0.f, 0.f};

    const int arow = wr * 64 + (lane & 15);
    const int brow = wc * 64 + (lane & 15);
    const int kk = (lane >> 4) * 8;

    const int ksteps = K >> 5;
    for (int s = 0; s < ksteps; ++s) {
        const int k0 = s * 32;
        const f16* Ag = A + (size_t)(m0 + ar0) * lda + k0 + kq;
        const f16* Wg = W + (size_t)(n0 + ar0) * ldw + k0 + kq;
#if HAVE_GLL
        __syncthreads();
        gll16(smA + wv * 512, Ag);
        gll16(smA + 2048 + wv * 512, Ag + (size_t)64 * lda);
        gll16(smB + wv * 512, Wg);
        gll16(smB + 2048 + wv * 512, Wg + (size_t)64 * ldw);
        __syncthreads();
#else
        uint4 va0 = *(const uint4*)Ag;
        uint4 va1 = *(const uint4*)(Ag + (size_t)64 * lda);
        uint4 vb0 = *(const uint4*)Wg;
        uint4 vb1 = *(const uint4*)(Wg + (size_t)64 * ldw);
        __syncthreads();
        *(uint4*)(smA + tid * 8) = va0;
        *(uint4*)(smA + (tid + 256) * 8) = va1;
        *(uint4*)(smB + tid * 8) = vb0;
        *(uint4*)(smB + (tid + 256) * 8) = vb1;
        __syncthreads();
#endif
        f16x8 af[4], bfr[4];
#pragma unroll
        for (int m = 0; m < 4; m++)
            af[m] = *(const f16x8*)(smA + (arow + m * 16) * 32 + kk);
#pragma unroll
        for (int n = 0; n < 4; n++)
            bfr[n] = *(const f16x8*)(smB + (brow + n * 16) * 32 + kk);
#pragma unroll
        for (int m = 0; m < 4; m++)
#pragma unroll
            for (int n = 0; n < 4; n++)
                acc[m][n] = __builtin_amdgcn_mfma_f32_16x16x32_f16(
                    af[m], bfr[n], acc[m][n], 0, 0, 0);
    }

    const int fr = lane & 15, fq = lane >> 4;
#pragma unroll
    for (int m = 0; m < 4; m++) {
        const int row0 = m0 + wr * 64 + m * 16 + fq * 4;
#pragma unroll
        for (int n = 0; n < 4; n++) {
            const int col = n0 + wc * 64 + n * 16 + fr;
            float bb = 0.f;
            if (BIAS) bb += bias1[col];
            if (B2) bb += bias2[col];
            int nb = 0, cl = 0;
            if (PERM) {
                int g = col >> 9;
                int unit = col & 511;
                nb = unit >> 3;
                cl = ((unit & 7) << 2) | g;
            }
#pragma unroll
            for (int r = 0; r < 4; r++) {
                float v = acc[m][n][r] + bb;
                if (PERM) {
                    int bt = row0 + r;
                    int b_ = bt >> 6, tt = bt & 63;
                    C[((size_t)(tt * 64 + nb) * 32 + b_) * 32 + cl] = (OUT)v;
                } else {
                    C[(size_t)(row0 + r) * ldc + col] = (OUT)v;
                }
            }
        }
    }
}

// ---------------- MEGA kernel: scan + feeders + logits consumers ----------
// blocks 0-63: scan (R6 structure verbatim; h history -> hseq[t][b][512] sc1
//   packed store placed after flag publish, drained by next step's vmcnt ->
//   hseq(t) valid when all flags >= t+2; epilogue publishes flag=66).
// blocks 64-95: feeders (1/b): poll flags>=t+2, read hseq(t)[b], compute
//   q -> w -> applied -> outs(t)[b][512] (fdot2, pair-packed weights), sc1
//   store, drain, oflag[b]=t+1.
// blocks 96-247: consumers: per 8-step group g poll oflags>=8g+8, then
//   process 128x128 logits tiles (A=outs rows via sc1 burst->LDS, B=W_out_h
//   via global_load_lds, MFMA), write fp32 logits + b_out.
// 248 blocks x 141KB LDS = 1 block/CU -> all co-resident regardless of
// dispatch order; consumers are pure consumers (no deadlock even if late).

constexpr int LDS_BYTES = 141312;  // max(consumer 133120+8192, scan 37376)

__global__ __launch_bounds__(256, 1) void mega(
    const float* __restrict__ gxp, const f16* __restrict__ Wfrag,
    const float* __restrict__ c0, f16* __restrict__ xbuf,
    unsigned* __restrict__ flags, f16* __restrict__ hseq,
    float* __restrict__ hout, float* __restrict__ cout,
    const uint4* __restrict__ wattQ, const f16* __restrict__ enc_h,
    const uint4* __restrict__ wcombQ, const float* __restrict__ b_comb,
    f16* __restrict__ outsP, unsigned* __restrict__ oflag,
    const f16* __restrict__ W_out_h, const float* __restrict__ b_out,
    float* __restrict__ logits) {
    __shared__ __align__(16) char lds[LDS_BYTES];
    const int bid = blockIdx.x;
    const int tid = threadIdx.x;
    const int lane = tid & 63, wv = tid >> 6;

    if (bid < NBLK) {
        // ================= SCAN =================
        const int n = bid;
        const int mi = wv >> 1, ni = wv & 1;
        f16(*hst)[520] = (f16(*)[520])lds;              // 33280 B
        float(*gl)[32] = (float(*)[32])(lds + 33280);   // 4096 B

        f16x8 bf[16];
        const f16* wbase =
            Wfrag + (size_t)((n * 2 + ni) * 16) * 512 + lane * 8;
#pragma unroll
        for (int ks = 0; ks < 16; ks++)
            bf[ks] = *(const f16x8*)(wbase + ks * 512);

        const int bb = tid >> 3, ul = tid & 7;
        const int unit = n * 8 + ul;
        float c = c0[bb * 512 + unit];
        float h = 0.f;

        const int sb = (tid & 63) >> 1;
        const int su0 = (tid & 1) * 4;
        const int arow = mi * 16 + (lane & 15);
        const int kcol0 = (lane >> 4) * 8;
        const int fr = lane & 15, fq = lane >> 4;

        for (int t = 0; t < T; ++t) {
            float4 gx4 = *(const float4*)(gxp +
                ((size_t)(t * NBLK + n) * 32 + bb) * 32 + ul * 4);
            for (;;) {
                unsigned v = ld_u32_cg(flags + lane);
                if (__all(v >= (unsigned)t)) break;
                __builtin_amdgcn_s_sleep(1);
            }
            asm volatile("" ::: "memory");
            const u64t* src = (const u64t*)(xbuf + (t & 1) * (B * H));
            u64t v[16];
#pragma unroll
            for (int i = 0; i < 16; i++) v[i] = ld_u64_cg(src + i * 256 + tid);
#pragma unroll
            for (int i = 0; i < 16; i++) {
                int np = i * 4 + wv;
                *(u64t*)(&hst[sb][np * 8 + su0]) = v[i];
            }
            __syncthreads();
            f32x4 acc0 = {0.f, 0.f, 0.f, 0.f}, acc1 = {0.f, 0.f, 0.f, 0.f};
#pragma unroll
            for (int ks = 0; ks < 16; ks++) {
                f16x8 af = *(const f16x8*)(&hst[arow][ks * 32 + kcol0]);
                if (ks & 1)
                    acc1 = __builtin_amdgcn_mfma_f32_16x16x32_f16(af, bf[ks],
                                                                  acc1, 0, 0, 0);
                else
                    acc0 = __builtin_amdgcn_mfma_f32_16x16x32_f16(af, bf[ks],
                                                                  acc0, 0, 0, 0);
            }
#pragma unroll
            for (int r = 0; r < 4; r++)
                gl[mi * 16 + fq * 4 + r][ni * 16 + fr] = acc0[r] + acc1[r];
            __syncthreads();
            float4 gv = *(const float4*)&gl[bb][ul * 4];
            float gi = gv.x + gx4.x;
            float gf = gv.y + gx4.y;
            float gg = gv.z + gx4.z;
            float go = gv.w + gx4.w;
            c = sigf(gf) * c + sigf(gi) * tanhf(gg);
            h = sigf(go) * tanhf(c);
            f16 hh = (f16)h;
            unsigned hv = (unsigned)__builtin_bit_cast(unsigned short, hh);
            unsigned other = (unsigned)__shfl_xor((int)hv, 1);
            unsigned packed = hv | (other << 16);
            f16* xn = xbuf + ((t + 1) & 1) * (B * H);
            if ((ul & 1) == 0)
                st_u32_cg((unsigned*)(xn + n * 256 + bb * 8 + ul), packed);
            if (t < T - 1) {
                asm volatile("s_waitcnt vmcnt(0)" ::: "memory");
                __syncthreads();
                if (tid == 0) st_u32_cg(flags + n, (unsigned)(t + 1));
            } else {
                __syncthreads();
            }
            // h history for feeders (off critical path; drained next step /
            // epilogue => valid at flags >= t+2)
            if ((ul & 1) == 0)
                st_u32_cg((unsigned*)(hseq + ((size_t)t * 32 + bb) * 512 +
                                      unit), packed);
        }
        // epilogue: drain hseq tail stores, publish terminal flag
        asm volatile("s_waitcnt vmcnt(0)" ::: "memory");
        __syncthreads();
        if (tid == 0) st_u32_cg(flags + n, 66u);
        hout[bb * 512 + unit] = h;
        cout[bb * 512 + unit] = c;

    } else if (bid < NBLK + NFEED) {
        // ================= FEEDER (one batch b) =================
        const int b = bid - NBLK;
        unsigned* hloc = (unsigned*)lds;            // 256 u32 (1KB)
        f16* qsh = (f16*)(lds + 1024);              // 1024 f16 (2KB)
        float* wsf = (float*)(lds + 3072);          // 64 f32
        f16* aph = (f16*)(lds + 3328);              // 1024 f16 (2KB)
        const unsigned* hseqU = (const unsigned*)hseq;
        unsigned* outsU = (unsigned*)outsP;

        for (int t = 0; t < T; ++t) {
            const unsigned target = (unsigned)(t + 2);
            for (;;) {
                unsigned v = ld_u32_cg(flags + lane);
                if (__all(v >= target)) break;
                __builtin_amdgcn_s_sleep(2);
            }
            asm volatile("" ::: "memory");
            hloc[tid] = ld_u32_cg(hseqU + ((size_t)t * 32 + b) * 256 + tid);
            __syncthreads();
            // ---- q[j] = h . W_att[j,:]  (4 cols per thread) ----
            float qv0 = 0, qv1 = 0, qv2 = 0, qv3 = 0;
            for (int k8 = 0; k8 < 64; ++k8) {
                uint4 hh = *(const uint4*)&hloc[k8 * 4];
                uint4 w0 = wattQ[(size_t)k8 * 1024 + tid];
                uint4 w1 = wattQ[(size_t)k8 * 1024 + tid + 256];
                uint4 w2 = wattQ[(size_t)k8 * 1024 + tid + 512];
                uint4 w3 = wattQ[(size_t)k8 * 1024 + tid + 768];
                qv0 = dot2f(hh.x, w0.x, qv0); qv0 = dot2f(hh.y, w0.y, qv0);
                qv0 = dot2f(hh.z, w0.z, qv0); qv0 = dot2f(hh.w, w0.w, qv0);
                qv1 = dot2f(hh.x, w1.x, qv1); qv1 = dot2f(hh.y, w1.y, qv1);
                qv1 = dot2f(hh.z, w1.z, qv1); qv1 = dot2f(hh.w, w1.w, qv1);
                qv2 = dot2f(hh.x, w2.x, qv2); qv2 = dot2f(hh.y, w2.y, qv2);
                qv2 = dot2f(hh.z, w2.z, qv2); qv2 = dot2f(hh.w, w2.w, qv2);
                qv3 = dot2f(hh.x, w3.x, qv3); qv3 = dot2f(hh.y, w3.y, qv3);
                qv3 = dot2f(hh.z, w3.z, qv3); qv3 = dot2f(hh.w, w3.w, qv3);
            }
            qsh[tid] = (f16)qv0;
            qsh[tid + 256] = (f16)qv1;
            qsh[tid + 512] = (f16)qv2;
            qsh[tid + 768] = (f16)qv3;
            __syncthreads();
            // ---- w[s] = q . enc[b][s]  (4 threads per s) ----
            {
                int s = tid >> 2, part = tid & 3;
                const unsigned* encp = (const unsigned*)enc_h +
                                       ((size_t)(b * 64 + s)) * 512 + part * 128;
                const unsigned* qp = (const unsigned*)qsh + part * 128;
                float wa = 0.f;
                for (int i = 0; i < 32; ++i) {
                    uint4 e4 = *(const uint4*)&encp[i * 4];
                    uint4 q4 = *(const uint4*)&qp[i * 4];
                    wa = dot2f(q4.x, e4.x, wa);
                    wa = dot2f(q4.y, e4.y, wa);
                    wa = dot2f(q4.z, e4.z, wa);
                    wa = dot2f(q4.w, e4.w, wa);
                }
                wa += __shfl_xor(wa, 1);
                wa += __shfl_xor(wa, 2);
                if (part == 0) wsf[s] = wa;
            }
            __syncthreads();
            // ---- applied[d] = sum_s w[s] enc[b][s][d]  (4 d per thread) ----
            {
                float a0 = 0, a1 = 0, a2 = 0, a3 = 0;
                for (int s2 = 0; s2 < 64; ++s2) {
                    float w = wsf[s2];
                    const f16* er = enc_h + ((size_t)(b * 64 + s2)) * 1024 + tid;
                    a0 += w * (float)er[0];
                    a1 += w * (float)er[256];
                    a2 += w * (float)er[512];
                    a3 += w * (float)er[768];
                }
                aph[tid] = (f16)a0;
                aph[tid + 256] = (f16)a1;
                aph[tid + 512] = (f16)a2;
                aph[tid + 768] = (f16)a3;
            }
            __syncthreads();
            // ---- outs[j] = tanh(bcomb + [h;applied] . W_comb[j,:]) (2 j) ----
            {
                float o0 = 0, o1 = 0;
                for (int k8 = 0; k8 < 64; ++k8) {
                    uint4 hh = *(const uint4*)&hloc[k8 * 4];
                    uint4 w0 = wcombQ[(size_t)k8 * 512 + tid];
                    uint4 w1 = wcombQ[(size_t)k8 * 512 + tid + 256];
                    o0 = dot2f(hh.x, w0.x, o0); o0 = dot2f(hh.y, w0.y, o0);
                    o0 = dot2f(hh.z, w0.z, o0); o0 = dot2f(hh.w, w0.w, o0);
                    o1 = dot2f(hh.x, w1.x, o1); o1 = dot2f(hh.y, w1.y, o1);
                    o1 = dot2f(hh.z, w1.z, o1); o1 = dot2f(hh.w, w1.w, o1);
                }
                const unsigned* ap = (const unsigned*)aph;
                for (int k8 = 0; k8 < 128; ++k8) {
                    uint4 aa = *(const uint4*)&ap[k8 * 4];
                    uint4 w0 = wcombQ[(size_t)(64 + k8) * 512 + tid];
                    uint4 w1 = wcombQ[(size_t)(64 + k8) * 512 + tid + 256];
                    o0 = dot2f(aa.x, w0.x, o0); o0 = dot2f(aa.y, w0.y, o0);
                    o0 = dot2f(aa.z, w0.z, o0); o0 = dot2f(aa.w, w0.w, o0);
                    o1 = dot2f(aa.x, w1.x, o1); o1 = dot2f(aa.y, w1.y, o1);
                    o1 = dot2f(aa.z, w1.z, o1); o1 = dot2f(aa.w, w1.w, o1);
                }
                o0 = tanhf(o0 + b_comb[tid]);
                o1 = tanhf(o1 + b_comb[tid + 256]);
                unsigned short s0 =
                    __builtin_bit_cast(unsigned short, (f16)o0);
                unsigned short s1 =
                    __builtin_bit_cast(unsigned short, (f16)o1);
                unsigned p0 = (unsigned)s0;
                unsigned p1 = (unsigned)s1;
                unsigned q0 = (unsigned)__shfl_xor((int)p0, 1);
                unsigned q1 = (unsigned)__shfl_xor((int)p1, 1);
                if ((tid & 1) == 0) {
                    size_t base = ((size_t)t * 32 + b) * 256;
                    st_u32_cg(outsU + base + (tid >> 1), p0 | (q0 << 16));
                    st_u32_cg(outsU + base + 128 + (tid >> 1),
                              p1 | (q1 << 16));
                }
            }
            asm volatile("s_waitcnt vmcnt(0)" ::: "memory");
            __syncthreads();
            if (tid == 0) st_u32_cg(oflag + b, (unsigned)(t + 1));
        }

    } else {
        // ================= LOGITS CONSUMER =================
        const int cc = bid - NBLK - NFEED;  // 0..151
        f16(*smA)[520] = (f16(*)[520])lds;           // 133120 B
        f16* smB = (f16*)(lds + 133120);             // 8192 B
        const int wr = wv >> 1, wc = wv & 1;
        const int ar0 = tid >> 2;
        const int kq = (tid & 3) * 8;
        const int fr = lane & 15, fq = lane >> 4;
        const int kk = (lane >> 4) * 8;

        for (int g = 0; g < 8; ++g) {
            const unsigned target = (unsigned)(g * 8 + 8);
            for (;;) {
                unsigned v = ld_u32_cg(oflag + (lane & 31));
                if (__all(v >= target)) break;
                __builtin_amdgcn_s_sleep(16);
            }
            asm volatile("" ::: "memory");
            for (int tix = cc; tix < 500; tix += NCONS) {
                const int mh = tix & 1, p = tix >> 1;
                __syncthreads();  // prior tile's smA reads done
                // stage A: 128 rows (row = b*8 + ti), half-row per thread
                // (outsP row = 512 f16 = 128 u64; hf2 half = 64 u64, 2 passes)
                {
                    int r = tid >> 1, hf2 = tid & 1;
                    int bA = (mh * 128 + r) >> 3;
                    int tA = g * 8 + (r & 7);
                    const u64t* srcA = (const u64t*)outsP +
                                       ((size_t)tA * 32 + bA) * 128 + hf2 * 64;
#pragma unroll
                    for (int j = 0; j < 2; ++j) {
                        u64t a[32];
#pragma unroll
                        for (int i = 0; i < 32; ++i)
                            a[i] = ld_u64_cg(srcA + j * 32 + i);
#pragma unroll
                        for (int i = 0; i < 32; ++i)
                            *(u64t*)(&smA[r][hf2 * 256 + j * 128 + i * 4]) =
                                a[i];
                    }
                }
                __syncthreads();
                f32x4 acc[4][4];
#pragma unroll
                for (int m = 0; m < 4; m++)
#pragma unroll
                    for (int nn = 0; nn < 4; nn++)
                        acc[m][nn] = {0.f, 0.f, 0.f, 0.f};
                for (int s = 0; s < 16; ++s) {
                    const f16* Wg = W_out_h +
                                    (size_t)(p * 128 + ar0) * 512 + s * 32 + kq;
                    if (s) __syncthreads();  // prev smB reads done
#if HAVE_GLL
                    gll16(smB + wv * 512, Wg);
                    gll16(smB + 2048 + wv * 512, Wg + (size_t)64 * 512);
#else
                    uint4 vb0 = *(const uint4*)Wg;
                    uint4 vb1 = *(const uint4*)(Wg + (size_t)64 * 512);
                    *(uint4*)(smB + tid * 8) = vb0;
                    *(uint4*)(smB + (tid + 256) * 8) = vb1;
#endif
                    __syncthreads();
                    f16x8 af[4], bfr[4];
#pragma unroll
                    for (int m = 0; m < 4; m++)
                        af[m] = *(const f16x8*)(&smA[wr * 64 + m * 16 + fr]
                                                    [s * 32 + kk]);
#pragma unroll
                    for (int nn = 0; nn < 4; nn++)
                        bfr[nn] = *(const f16x8*)(smB +
                                                  (wc * 64 + nn * 16 + fr) * 32 +
                                                  kk);
#pragma unroll
                    for (int m = 0; m < 4; m++)
#pragma unroll
                        for (int nn = 0; nn < 4; nn++)
                            acc[m][nn] = __builtin_amdgcn_mfma_f32_16x16x32_f16(
                                af[m], bfr[nn], acc[m][nn], 0, 0, 0);
                }
                // epilogue
#pragma unroll
                for (int m = 0; m < 4; m++) {
                    const int row0 = wr * 64 + m * 16 + fq * 4;
#pragma unroll
                    for (int nn = 0; nn < 4; nn++) {
                        const int col = p * 128 + wc * 64 + nn * 16 + fr;
                        const float bo = b_out[col];
#pragma unroll
                        for (int r = 0; r < 4; r++) {
                            int rowT = mh * 128 + row0 + r;
                            int bC = rowT >> 3;
                            int btC = bC * 64 + g * 8 + (rowT & 7);
                            logits[(size_t)btC * 32000 + col] =
                                acc[m][nn][r] + bo;
                        }
                    }
                }
            }
        }
    }
}

// ---------------- launcher ----------------

extern "C" void kernel_launch(void* const* d_in, const int* in_sizes, int n_in,
                              void* d_out, int out_size, void* d_ws,
                              size_t ws_size, hipStream_t stream) {
    const int* tok = (const int*)d_in[0];
    const float* enc = (const float*)d_in[1];
    const float* h0 = (const float*)d_in[2];
    const float* c0 = (const float*)d_in[3];
    const float* emb = (const float*)d_in[4];
    const float* W_ih = (const float*)d_in[5];
    const float* W_hh = (const float*)d_in[6];
    const float* b_ih = (const float*)d_in[7];
    const float* b_hh = (const float*)d_in[8];
    const float* W_att = (const float*)d_in[9];
    const float* W_comb = (const float*)d_in[10];
    const float* b_comb = (const float*)d_in[11];
    const float* W_out = (const float*)d_in[12];
    const float* b_out = (const float*)d_in[13];

    float* out_logits = (float*)d_out;
    float* out_h = out_logits + (size_t)BT * V;
    float* out_c = out_h + (size_t)B * H;

    char* p = (char*)d_ws;
    auto alloc = [&](size_t bytes) -> void* {
        void* r = (void*)p;
        p += (bytes + 255) & ~(size_t)255;
        return r;
    };
    f16* W_ih_h = (f16*)alloc((size_t)G4 * E * 2);           // 2MB
    f16* Wfrag = (f16*)alloc((size_t)NBLK * 2 * 16 * 64 * 8 * 2);  // 2MB
    f16* W_out_h = (f16*)alloc((size_t)V * 512 * 2);         // 32MB
    f16* enc_h = (f16*)alloc((size_t)B * S * 1024 * 2);      // 4MB
    uint4* wattQ = (uint4*)alloc((size_t)64 * 1024 * 16);    // 1MB
    uint4* wcombQ = (uint4*)alloc((size_t)192 * 512 * 16);   // 1.5MB
    f16* x_h = (f16*)alloc((size_t)BT * E * 2);              // 2MB
    float* gxp = (float*)alloc((size_t)T * NBLK * 32 * 32 * 4);  // 16MB
    f16* hseq = (f16*)alloc((size_t)T * B * 512 * 2);        // 2MB
    f16* outsP = (f16*)alloc((size_t)T * B * 512 * 2);       // 2MB
    f16* xbuf = (f16*)alloc((size_t)2 * B * H * 2);          // 128KB
    unsigned* flags = (unsigned*)alloc(256);
    unsigned* oflag = (unsigned*)alloc(256);

    cvt_f16<<<512, 256, 0, stream>>>(W_ih, W_ih_h, G4 * E / 4);
    cvt_f16<<<2048, 256, 0, stream>>>(W_out, W_out_h, V * 512 / 4);
    cvt_f16<<<1024, 256, 0, stream>>>(enc, enc_h, B * S * 1024 / 4);
    pack_wfrag<<<512, 256, 0, stream>>>(W_hh, Wfrag);
    pack_watt4<<<256, 256, 0, stream>>>(W_att, wattQ);
    pack_wcomb4<<<384, 256, 0, stream>>>(W_comb, wcombQ);
    gather_x<<<1024, 256, 0, stream>>>(tok, emb, x_h);
    init_h0<<<64, 256, 0, stream>>>(h0, xbuf, flags, oflag);

    // gates_x = x @ W_ih^T + b_ih + b_hh, permuted for the scan
    gemm_bt<true, true, true, float><<<dim3(16, 16), 256, 0, stream>>>(
        x_h, E, W_ih_h, E, gxp, 0, E, b_ih, b_hh);

    // fused scan + attention feeders + logits consumers
    mega<<<NBLK + NFEED + NCONS, 256, 0, stream>>>(
        gxp, Wfrag, c0, xbuf, flags, hseq, out_h, out_c, wattQ, enc_h, wcombQ,
        b_comb, outsP, oflag, W_out_h, b_out, out_logits);
}

// Round 14
// 1954.721 us; speedup vs baseline: 1.1531x; 1.1531x over previous
//
#include <hip/hip_runtime.h>
#include <hip/hip_fp16.h>

typedef _Float16 f16;
typedef _Float16 f16x2 __attribute__((ext_vector_type(2)));
typedef _Float16 f16x4 __attribute__((ext_vector_type(4)));
typedef _Float16 f16x8 __attribute__((ext_vector_type(8)));
typedef float    f32x4 __attribute__((ext_vector_type(4)));
typedef unsigned long long u64t;

#define DEV __device__ __forceinline__

constexpr int B = 32, T = 64, S = 64, H = 512, E = 512, V = 32000;
constexpr int BT = B * T;      // 2048
constexpr int G4 = 4 * H;      // 2048
constexpr int NBLK = 64;       // scan blocks
constexpr int NFEED = 32;      // feeder blocks (1 per batch)

DEV float sigf(float x) { return 1.f / (1.f + expf(-x)); }

#if defined(__has_builtin)
#if __has_builtin(__builtin_amdgcn_global_load_lds)
#define HAVE_GLL 1
#endif
#if __has_builtin(__builtin_amdgcn_fdot2)
#define HAVE_FDOT2 1
#endif
#endif

DEV float dot2f(unsigned a, unsigned b, float c) {
#if HAVE_FDOT2
    return __builtin_amdgcn_fdot2(__builtin_bit_cast(f16x2, a),
                                  __builtin_bit_cast(f16x2, b), c, false);
#else
    f16x2 av = __builtin_bit_cast(f16x2, a);
    f16x2 bv = __builtin_bit_cast(f16x2, b);
    return c + (float)av.x * (float)bv.x + (float)av.y * (float)bv.y;
#endif
}

// relaxed agent-scope = plain sc1 loads/stores (MALL-coherent, no wbl2/inv)
DEV u64t ld_u64_cg(const u64t* p) {
    return __hip_atomic_load(p, __ATOMIC_RELAXED, __HIP_MEMORY_SCOPE_AGENT);
}
DEV unsigned ld_u32_cg(const unsigned* p) {
    return __hip_atomic_load(p, __ATOMIC_RELAXED, __HIP_MEMORY_SCOPE_AGENT);
}
DEV void st_u32_cg(unsigned* p, unsigned v) {
    __hip_atomic_store(p, v, __ATOMIC_RELAXED, __HIP_MEMORY_SCOPE_AGENT);
}

#if HAVE_GLL
DEV void gll16(f16* lds, const f16* g) {
    __builtin_amdgcn_global_load_lds(
        (const __attribute__((address_space(1))) void*)g,
        (__attribute__((address_space(3))) void*)lds, 16, 0, 0);
}
#endif

DEV unsigned pkh2(float a, float b) {
    f16x2 h = {(f16)a, (f16)b};
    return __builtin_bit_cast(unsigned, h);
}

// ---------------- converts / packing ----------------

__global__ __launch_bounds__(256) void cvt_f16(const float* __restrict__ s,
                                               f16* __restrict__ d, int n4) {
    for (int i = blockIdx.x * blockDim.x + threadIdx.x; i < n4;
         i += gridDim.x * blockDim.x) {
        float4 v = ((const float4*)s)[i];
        f16x4 o = {(f16)v.x, (f16)v.y, (f16)v.z, (f16)v.w};
        ((f16x4*)d)[i] = o;
    }
}

// Pack W_hh [2048][512] f32 into MFMA B-fragment order, f16 (R6 layout).
__global__ __launch_bounds__(256) void pack_wfrag(const float* __restrict__ W,
                                                  f16* __restrict__ Wf) {
    int id = blockIdx.x * 256 + threadIdx.x;  // 2^17 total
    if (id >= NBLK * 2 * 16 * 64) return;
    int lane = id & 63;
    int ks = (id >> 6) & 15;
    int ni = (id >> 10) & 1;
    int n = id >> 11;
    int cl = ni * 16 + (lane & 15);
    int ul = cl >> 2, g = cl & 3;
    int unit = n * 8 + ul;
    int k = ks * 32 + (lane >> 4) * 8;
    const float* src = W + (size_t)(g * 512 + unit) * 512 + k;
    float4 a = *(const float4*)src;
    float4 b = *(const float4*)(src + 4);
    f16x8 o = {(f16)a.x, (f16)a.y, (f16)a.z, (f16)a.w,
               (f16)b.x, (f16)b.y, (f16)b.z, (f16)b.w};
    *(f16x8*)(Wf + (size_t)id * 8) = o;
}

// wattP4 uint4[k8 (64)][j (1024)] : 4 packed f16-pairs of W_att[j][k8*8 ..+8)
__global__ __launch_bounds__(256) void pack_watt4(const float* __restrict__ W,
                                                  uint4* __restrict__ P) {
    int id = blockIdx.x * 256 + threadIdx.x;
    if (id >= 64 * 1024) return;
    int j = id & 1023, k8 = id >> 10;
    const float* src = W + (size_t)j * 512 + k8 * 8;
    float4 a = *(const float4*)src;
    float4 b = *(const float4*)(src + 4);
    uint4 o = {pkh2(a.x, a.y), pkh2(a.z, a.w), pkh2(b.x, b.y), pkh2(b.z, b.w)};
    P[(size_t)k8 * 1024 + j] = o;
}

// wcombP4 uint4[k8 (192)][j (512)] : pairs of W_comb[j][k8*8 ..+8)
__global__ __launch_bounds__(256) void pack_wcomb4(const float* __restrict__ W,
                                                   uint4* __restrict__ P) {
    int id = blockIdx.x * 256 + threadIdx.x;
    if (id >= 192 * 512) return;
    int j = id & 511, k8 = id >> 9;
    const float* src = W + (size_t)j * 1536 + k8 * 8;
    float4 a = *(const float4*)src;
    float4 b = *(const float4*)(src + 4);
    uint4 o = {pkh2(a.x, a.y), pkh2(a.z, a.w), pkh2(b.x, b.y), pkh2(b.z, b.w)};
    P[(size_t)k8 * 512 + j] = o;
}

// x[bt][e] = (f16) emb[tok[bt]][e]
__global__ __launch_bounds__(256) void gather_x(const int* __restrict__ tok,
                                                const float* __restrict__ emb,
                                                f16* __restrict__ x) {
    int id = blockIdx.x * blockDim.x + threadIdx.x;  // 2048*128
    if (id >= BT * (E / 4)) return;
    int row = id >> 7;
    int e4 = (id & 127) * 4;
    int t = tok[row];
    float4 v = *(const float4*)(emb + (size_t)t * E + e4);
    f16x4 o = {(f16)v.x, (f16)v.y, (f16)v.z, (f16)v.w};
    ((f16x4*)x)[id] = o;
}

// stage h0 into xbuf[0] (block-major) and reset flags (replay safe)
__global__ __launch_bounds__(256) void init_h0(const float* __restrict__ h0,
                                               f16* __restrict__ xbuf,
                                               unsigned* __restrict__ fl) {
    int i = blockIdx.x * 256 + threadIdx.x;  // 64 blocks -> 16384
    if (i < B * H) {
        int nn = i >> 8;
        int bb = (i >> 3) & 31;
        int ul = i & 7;
        xbuf[i] = (f16)h0[bb * 512 + nn * 8 + ul];
    }
    if (i < NBLK) fl[i] = 0u;
}

// ---------------- GEMM (proven): C = A @ W^T (+bias); PERM / MSWAP opts ----

template <bool BIAS, bool B2, bool PERM, bool MSWAP, typename OUT>
__global__ __launch_bounds__(256) void gemm_bt(
    const f16* __restrict__ A, int lda, const f16* __restrict__ W, int ldw,
    OUT* __restrict__ C, int ldc, int K, const float* __restrict__ bias1,
    const float* __restrict__ bias2) {
    __shared__ f16 smA[128 * 32];
    __shared__ f16 smB[128 * 32];
    const int tid = threadIdx.x;
    const int lane = tid & 63;
    const int wv = tid >> 6;
    const int wr = wv >> 1, wc = wv & 1;
    const int m0 = (MSWAP ? blockIdx.x : blockIdx.y) * 128;
    const int n0 = (MSWAP ? blockIdx.y : blockIdx.x) * 128;
    const int ar0 = tid >> 2;
    const int kq = (tid & 3) * 8;

    f32x4 acc[4][4];
#pragma unroll
    for (int m = 0; m < 4; m++)
#pragma unroll
        for (int n = 0; n < 4; n++) acc[m][n] = {0.f, 0.f, 0.f, 0.f};

    const int arow = wr * 64 + (lane & 15);
    const int brow = wc * 64 + (lane & 15);
    const int kk = (lane >> 4) * 8;

    const int ksteps = K >> 5;
    for (int s = 0; s < ksteps; ++s) {
        const int k0 = s * 32;
        const f16* Ag = A + (size_t)(m0 + ar0) * lda + k0 + kq;
        const f16* Wg = W + (size_t)(n0 + ar0) * ldw + k0 + kq;
#if HAVE_GLL
        __syncthreads();
        gll16(smA + wv * 512, Ag);
        gll16(smA + 2048 + wv * 512, Ag + (size_t)64 * lda);
        gll16(smB + wv * 512, Wg);
        gll16(smB + 2048 + wv * 512, Wg + (size_t)64 * ldw);
        __syncthreads();
#else
        uint4 va0 = *(const uint4*)Ag;
        uint4 va1 = *(const uint4*)(Ag + (size_t)64 * lda);
        uint4 vb0 = *(const uint4*)Wg;
        uint4 vb1 = *(const uint4*)(Wg + (size_t)64 * ldw);
        __syncthreads();
        *(uint4*)(smA + tid * 8) = va0;
        *(uint4*)(smA + (tid + 256) * 8) = va1;
        *(uint4*)(smB + tid * 8) = vb0;
        *(uint4*)(smB + (tid + 256) * 8) = vb1;
        __syncthreads();
#endif
        f16x8 af[4], bfr[4];
#pragma unroll
        for (int m = 0; m < 4; m++)
            af[m] = *(const f16x8*)(smA + (arow + m * 16) * 32 + kk);
#pragma unroll
        for (int n = 0; n < 4; n++)
            bfr[n] = *(const f16x8*)(smB + (brow + n * 16) * 32 + kk);
#pragma unroll
        for (int m = 0; m < 4; m++)
#pragma unroll
            for (int n = 0; n < 4; n++)
                acc[m][n] = __builtin_amdgcn_mfma_f32_16x16x32_f16(
                    af[m], bfr[n], acc[m][n], 0, 0, 0);
    }

    const int fr = lane & 15, fq = lane >> 4;
#pragma unroll
    for (int m = 0; m < 4; m++) {
        const int row0 = m0 + wr * 64 + m * 16 + fq * 4;
#pragma unroll
        for (int n = 0; n < 4; n++) {
            const int col = n0 + wc * 64 + n * 16 + fr;
            float bb = 0.f;
            if (BIAS) bb += bias1[col];
            if (B2) bb += bias2[col];
            int nb = 0, cl = 0;
            if (PERM) {
                int g = col >> 9;
                int unit = col & 511;
                nb = unit >> 3;
                cl = ((unit & 7) << 2) | g;
            }
#pragma unroll
            for (int r = 0; r < 4; r++) {
                float v = acc[m][n][r] + bb;
                if (PERM) {
                    int bt = row0 + r;
                    int b_ = bt >> 6, tt = bt & 63;
                    C[((size_t)(tt * 64 + nb) * 32 + b_) * 32 + cl] = (OUT)v;
                } else {
                    C[(size_t)(row0 + r) * ldc + col] = (OUT)v;
                }
            }
        }
    }
}

// ---------------- mega96: scan (0-63) + attention feeders (64-95) ----------
// Scan: R6/R13-verified structure; publishes h(t) into hseq[t][b][512] via
//   sc1 (drained by next step's vmcnt -> valid when all flags >= t+2);
//   epilogue publishes flag=66.
// Feeders (1/batch): poll flags >= t+2, read hseq(t)[b], compute
//   q -> w -> applied -> outs(t) (fdot2, per-XCD-L2-resident packed weights),
//   write outs bt-major via sc1. One-way dataflow: scan never waits on
//   feeders -> no deadlock regardless of residency/dispatch order.
// NO logits consumers in-kernel (R13 lesson: their MALL traffic wrecks the
// scan cadence); logits GEMM is a separate post-kernel.

constexpr int LDS_BYTES = 37376;

__global__ __launch_bounds__(256, 1) void mega96(
    const float* __restrict__ gxp, const f16* __restrict__ Wfrag,
    const float* __restrict__ c0, f16* __restrict__ xbuf,
    unsigned* __restrict__ flags, f16* __restrict__ hseq,
    float* __restrict__ hout, float* __restrict__ cout,
    const uint4* __restrict__ wattQ, const f16* __restrict__ enc_h,
    const uint4* __restrict__ wcombQ, const float* __restrict__ b_comb,
    f16* __restrict__ outsP) {
    __shared__ __align__(16) char lds[LDS_BYTES];
    const int bid = blockIdx.x;
    const int tid = threadIdx.x;
    const int lane = tid & 63, wv = tid >> 6;

    if (bid < NBLK) {
        // ================= SCAN =================
        const int n = bid;
        const int mi = wv >> 1, ni = wv & 1;
        f16(*hst)[520] = (f16(*)[520])lds;              // 33280 B
        float(*gl)[32] = (float(*)[32])(lds + 33280);   // 4096 B

        f16x8 bf[16];
        const f16* wbase =
            Wfrag + (size_t)((n * 2 + ni) * 16) * 512 + lane * 8;
#pragma unroll
        for (int ks = 0; ks < 16; ks++)
            bf[ks] = *(const f16x8*)(wbase + ks * 512);

        const int bb = tid >> 3, ul = tid & 7;
        const int unit = n * 8 + ul;
        float c = c0[bb * 512 + unit];
        float h = 0.f;

        const int sb = (tid & 63) >> 1;
        const int su0 = (tid & 1) * 4;
        const int arow = mi * 16 + (lane & 15);
        const int kcol0 = (lane >> 4) * 8;
        const int fr = lane & 15, fq = lane >> 4;

        for (int t = 0; t < T; ++t) {
            float4 gx4 = *(const float4*)(gxp +
                ((size_t)(t * NBLK + n) * 32 + bb) * 32 + ul * 4);
            for (;;) {
                unsigned v = ld_u32_cg(flags + lane);
                if (__all(v >= (unsigned)t)) break;
                __builtin_amdgcn_s_sleep(1);
            }
            asm volatile("" ::: "memory");
            const u64t* src = (const u64t*)(xbuf + (t & 1) * (B * H));
            u64t v[16];
#pragma unroll
            for (int i = 0; i < 16; i++) v[i] = ld_u64_cg(src + i * 256 + tid);
#pragma unroll
            for (int i = 0; i < 16; i++) {
                int np = i * 4 + wv;
                *(u64t*)(&hst[sb][np * 8 + su0]) = v[i];
            }
            __syncthreads();
            f32x4 acc0 = {0.f, 0.f, 0.f, 0.f}, acc1 = {0.f, 0.f, 0.f, 0.f};
#pragma unroll
            for (int ks = 0; ks < 16; ks++) {
                f16x8 af = *(const f16x8*)(&hst[arow][ks * 32 + kcol0]);
                if (ks & 1)
                    acc1 = __builtin_amdgcn_mfma_f32_16x16x32_f16(af, bf[ks],
                                                                  acc1, 0, 0, 0);
                else
                    acc0 = __builtin_amdgcn_mfma_f32_16x16x32_f16(af, bf[ks],
                                                                  acc0, 0, 0, 0);
            }
#pragma unroll
            for (int r = 0; r < 4; r++)
                gl[mi * 16 + fq * 4 + r][ni * 16 + fr] = acc0[r] + acc1[r];
            __syncthreads();
            float4 gv = *(const float4*)&gl[bb][ul * 4];
            float gi = gv.x + gx4.x;
            float gf = gv.y + gx4.y;
            float gg = gv.z + gx4.z;
            float go = gv.w + gx4.w;
            c = sigf(gf) * c + sigf(gi) * tanhf(gg);
            h = sigf(go) * tanhf(c);
            f16 hh = (f16)h;
            unsigned hv = (unsigned)__builtin_bit_cast(unsigned short, hh);
            unsigned other = (unsigned)__shfl_xor((int)hv, 1);
            unsigned packed = hv | (other << 16);
            f16* xn = xbuf + ((t + 1) & 1) * (B * H);
            if ((ul & 1) == 0)
                st_u32_cg((unsigned*)(xn + n * 256 + bb * 8 + ul), packed);
            if (t < T - 1) {
                asm volatile("s_waitcnt vmcnt(0)" ::: "memory");
                __syncthreads();
                if (tid == 0) st_u32_cg(flags + n, (unsigned)(t + 1));
            } else {
                __syncthreads();
            }
            // h history for feeders (off critical path; drained next step /
            // epilogue => valid at flags >= t+2)
            if ((ul & 1) == 0)
                st_u32_cg((unsigned*)(hseq + ((size_t)t * 32 + bb) * 512 +
                                      unit), packed);
        }
        // epilogue: drain hseq tail stores, publish terminal flag
        asm volatile("s_waitcnt vmcnt(0)" ::: "memory");
        __syncthreads();
        if (tid == 0) st_u32_cg(flags + n, 66u);
        hout[bb * 512 + unit] = h;
        cout[bb * 512 + unit] = c;

    } else {
        // ================= FEEDER (one batch b) =================
        const int b = bid - NBLK;
        unsigned* hloc = (unsigned*)lds;            // 256 u32 (1KB)
        f16* qsh = (f16*)(lds + 1024);              // 1024 f16 (2KB)
        float* wsf = (float*)(lds + 3072);          // 64 f32
        f16* aph = (f16*)(lds + 3328);              // 1024 f16 (2KB)
        const unsigned* hseqU = (const unsigned*)hseq;
        unsigned* outsU = (unsigned*)outsP;

        for (int t = 0; t < T; ++t) {
            const unsigned target = (unsigned)(t + 2);
            for (;;) {
                unsigned v = ld_u32_cg(flags + lane);
                if (__all(v >= target)) break;
                __builtin_amdgcn_s_sleep(2);
            }
            asm volatile("" ::: "memory");
            hloc[tid] = ld_u32_cg(hseqU + ((size_t)t * 32 + b) * 256 + tid);
            __syncthreads();
            // ---- q[j] = h . W_att[j,:]  (4 cols per thread) ----
            float qv0 = 0, qv1 = 0, qv2 = 0, qv3 = 0;
            for (int k8 = 0; k8 < 64; ++k8) {
                uint4 hh = *(const uint4*)&hloc[k8 * 4];
                uint4 w0 = wattQ[(size_t)k8 * 1024 + tid];
                uint4 w1 = wattQ[(size_t)k8 * 1024 + tid + 256];
                uint4 w2 = wattQ[(size_t)k8 * 1024 + tid + 512];
                uint4 w3 = wattQ[(size_t)k8 * 1024 + tid + 768];
                qv0 = dot2f(hh.x, w0.x, qv0); qv0 = dot2f(hh.y, w0.y, qv0);
                qv0 = dot2f(hh.z, w0.z, qv0); qv0 = dot2f(hh.w, w0.w, qv0);
                qv1 = dot2f(hh.x, w1.x, qv1); qv1 = dot2f(hh.y, w1.y, qv1);
                qv1 = dot2f(hh.z, w1.z, qv1); qv1 = dot2f(hh.w, w1.w, qv1);
                qv2 = dot2f(hh.x, w2.x, qv2); qv2 = dot2f(hh.y, w2.y, qv2);
                qv2 = dot2f(hh.z, w2.z, qv2); qv2 = dot2f(hh.w, w2.w, qv2);
                qv3 = dot2f(hh.x, w3.x, qv3); qv3 = dot2f(hh.y, w3.y, qv3);
                qv3 = dot2f(hh.z, w3.z, qv3); qv3 = dot2f(hh.w, w3.w, qv3);
            }
            qsh[tid] = (f16)qv0;
            qsh[tid + 256] = (f16)qv1;
            qsh[tid + 512] = (f16)qv2;
            qsh[tid + 768] = (f16)qv3;
            __syncthreads();
            // ---- w[s] = q . enc[b][s]  (4 threads per s) ----
            {
                int s = tid >> 2, part = tid & 3;
                const unsigned* encp = (const unsigned*)enc_h +
                                       ((size_t)(b * 64 + s)) * 512 + part * 128;
                const unsigned* qp = (const unsigned*)qsh + part * 128;
                float wa = 0.f;
                for (int i = 0; i < 32; ++i) {
                    uint4 e4 = *(const uint4*)&encp[i * 4];
                    uint4 q4 = *(const uint4*)&qp[i * 4];
                    wa = dot2f(q4.x, e4.x, wa);
                    wa = dot2f(q4.y, e4.y, wa);
                    wa = dot2f(q4.z, e4.z, wa);
                    wa = dot2f(q4.w, e4.w, wa);
                }
                wa += __shfl_xor(wa, 1);
                wa += __shfl_xor(wa, 2);
                if (part == 0) wsf[s] = wa;
            }
            __syncthreads();
            // ---- applied[d] = sum_s w[s] enc[b][s][d]  (4 d per thread) ----
            {
                float a0 = 0, a1 = 0, a2 = 0, a3 = 0;
                for (int s2 = 0; s2 < 64; ++s2) {
                    float w = wsf[s2];
                    const f16* er = enc_h + ((size_t)(b * 64 + s2)) * 1024 + tid;
                    a0 += w * (float)er[0];
                    a1 += w * (float)er[256];
                    a2 += w * (float)er[512];
                    a3 += w * (float)er[768];
                }
                aph[tid] = (f16)a0;
                aph[tid + 256] = (f16)a1;
                aph[tid + 512] = (f16)a2;
                aph[tid + 768] = (f16)a3;
            }
            __syncthreads();
            // ---- outs[j] = tanh(bcomb + [h;applied] . W_comb[j,:]) (2 j) ----
            {
                float o0 = 0, o1 = 0;
                for (int k8 = 0; k8 < 64; ++k8) {
                    uint4 hh = *(const uint4*)&hloc[k8 * 4];
                    uint4 w0 = wcombQ[(size_t)k8 * 512 + tid];
                    uint4 w1 = wcombQ[(size_t)k8 * 512 + tid + 256];
                    o0 = dot2f(hh.x, w0.x, o0); o0 = dot2f(hh.y, w0.y, o0);
                    o0 = dot2f(hh.z, w0.z, o0); o0 = dot2f(hh.w, w0.w, o0);
                    o1 = dot2f(hh.x, w1.x, o1); o1 = dot2f(hh.y, w1.y, o1);
                    o1 = dot2f(hh.z, w1.z, o1); o1 = dot2f(hh.w, w1.w, o1);
                }
                const unsigned* ap = (const unsigned*)aph;
                for (int k8 = 0; k8 < 128; ++k8) {
                    uint4 aa = *(const uint4*)&ap[k8 * 4];
                    uint4 w0 = wcombQ[(size_t)(64 + k8) * 512 + tid];
                    uint4 w1 = wcombQ[(size_t)(64 + k8) * 512 + tid + 256];
                    o0 = dot2f(aa.x, w0.x, o0); o0 = dot2f(aa.y, w0.y, o0);
                    o0 = dot2f(aa.z, w0.z, o0); o0 = dot2f(aa.w, w0.w, o0);
                    o1 = dot2f(aa.x, w1.x, o1); o1 = dot2f(aa.y, w1.y, o1);
                    o1 = dot2f(aa.z, w1.z, o1); o1 = dot2f(aa.w, w1.w, o1);
                }
                o0 = tanhf(o0 + b_comb[tid]);
                o1 = tanhf(o1 + b_comb[tid + 256]);
                unsigned short s0 =
                    __builtin_bit_cast(unsigned short, (f16)o0);
                unsigned short s1 =
                    __builtin_bit_cast(unsigned short, (f16)o1);
                unsigned p0 = (unsigned)s0;
                unsigned p1 = (unsigned)s1;
                unsigned q0 = (unsigned)__shfl_xor((int)p0, 1);
                unsigned q1 = (unsigned)__shfl_xor((int)p1, 1);
                if ((tid & 1) == 0) {
                    // bt-major: outs[(b*64+t)][512] f16 = 256 u32
                    size_t base = ((size_t)(b * 64 + t)) * 256;
                    st_u32_cg(outsU + base + (tid >> 1), p0 | (q0 << 16));
                    st_u32_cg(outsU + base + 128 + (tid >> 1),
                              p1 | (q1 << 16));
                }
            }
            __syncthreads();  // hloc/qsh/aph safe to overwrite next t
        }
        // outs stores flushed at kernel-boundary release
    }
}

// ---------------- launcher ----------------

extern "C" void kernel_launch(void* const* d_in, const int* in_sizes, int n_in,
                              void* d_out, int out_size, void* d_ws,
                              size_t ws_size, hipStream_t stream) {
    const int* tok = (const int*)d_in[0];
    const float* enc = (const float*)d_in[1];
    const float* h0 = (const float*)d_in[2];
    const float* c0 = (const float*)d_in[3];
    const float* emb = (const float*)d_in[4];
    const float* W_ih = (const float*)d_in[5];
    const float* W_hh = (const float*)d_in[6];
    const float* b_ih = (const float*)d_in[7];
    const float* b_hh = (const float*)d_in[8];
    const float* W_att = (const float*)d_in[9];
    const float* W_comb = (const float*)d_in[10];
    const float* b_comb = (const float*)d_in[11];
    const float* W_out = (const float*)d_in[12];
    const float* b_out = (const float*)d_in[13];

    float* out_logits = (float*)d_out;
    float* out_h = out_logits + (size_t)BT * V;
    float* out_c = out_h + (size_t)B * H;

    char* p = (char*)d_ws;
    auto alloc = [&](size_t bytes) -> void* {
        void* r = (void*)p;
        p += (bytes + 255) & ~(size_t)255;
        return r;
    };
    f16* W_ih_h = (f16*)alloc((size_t)G4 * E * 2);           // 2MB
    f16* Wfrag = (f16*)alloc((size_t)NBLK * 2 * 16 * 64 * 8 * 2);  // 2MB
    f16* W_out_h = (f16*)alloc((size_t)V * 512 * 2);         // 32MB
    f16* enc_h = (f16*)alloc((size_t)B * S * 1024 * 2);      // 4MB
    uint4* wattQ = (uint4*)alloc((size_t)64 * 1024 * 16);    // 1MB
    uint4* wcombQ = (uint4*)alloc((size_t)192 * 512 * 16);   // 1.5MB
    f16* x_h = (f16*)alloc((size_t)BT * E * 2);              // 2MB
    float* gxp = (float*)alloc((size_t)T * NBLK * 32 * 32 * 4);  // 16MB
    f16* hseq = (f16*)alloc((size_t)T * B * 512 * 2);        // 2MB
    f16* outsP = (f16*)alloc((size_t)BT * 512 * 2);          // 2MB (bt-major)
    f16* xbuf = (f16*)alloc((size_t)2 * B * H * 2);          // 128KB
    unsigned* flags = (unsigned*)alloc(256);

    cvt_f16<<<512, 256, 0, stream>>>(W_ih, W_ih_h, G4 * E / 4);
    cvt_f16<<<2048, 256, 0, stream>>>(W_out, W_out_h, V * 512 / 4);
    cvt_f16<<<1024, 256, 0, stream>>>(enc, enc_h, B * S * 1024 / 4);
    pack_wfrag<<<512, 256, 0, stream>>>(W_hh, Wfrag);
    pack_watt4<<<256, 256, 0, stream>>>(W_att, wattQ);
    pack_wcomb4<<<384, 256, 0, stream>>>(W_comb, wcombQ);
    gather_x<<<1024, 256, 0, stream>>>(tok, emb, x_h);
    init_h0<<<64, 256, 0, stream>>>(h0, xbuf, flags);

    // gates_x = x @ W_ih^T + b_ih + b_hh, permuted for the scan
    gemm_bt<true, true, true, false, float><<<dim3(16, 16), 256, 0, stream>>>(
        x_h, E, W_ih_h, E, gxp, 0, E, b_ih, b_hh);

    // fused scan + attention feeders (downstream of scan, hidden in its shadow)
    mega96<<<NBLK + NFEED, 256, 0, stream>>>(gxp, Wfrag, c0, xbuf, flags,
                                             hseq, out_h, out_c, wattQ, enc_h,
                                             wcombQ, b_comb, outsP);

    // logits = outs @ W_out^T + b_out   [2048 x 32000] fp32 -> d_out
    // MSWAP: m-tile on blockIdx.x so dispatch-adjacent blocks share W panel
    gemm_bt<true, false, false, true, float>
        <<<dim3(16, 250), 256, 0, stream>>>(outsP, 512, W_out_h, 512,
                                            out_logits, V, 512, b_out,
                                            nullptr);
}

// Round 15
// 1255.315 us; speedup vs baseline: 1.7956x; 1.5572x over previous
//
#include <hip/hip_runtime.h>
#include <hip/hip_fp16.h>

typedef _Float16 f16;
typedef _Float16 f16x2 __attribute__((ext_vector_type(2)));
typedef _Float16 f16x4 __attribute__((ext_vector_type(4)));
typedef _Float16 f16x8 __attribute__((ext_vector_type(8)));
typedef float    f32x4 __attribute__((ext_vector_type(4)));
typedef unsigned long long u64t;

#define DEV __device__ __forceinline__

constexpr int B = 32, T = 64, S = 64, H = 512, E = 512, V = 32000;
constexpr int BT = B * T;      // 2048
constexpr int G4 = 4 * H;      // 2048
constexpr int NBLK = 64;       // scan blocks
constexpr int NFEED = 32;      // feeder blocks (1 per batch)
constexpr int NCONS = 160;     // logits consumer blocks (even stride!)

DEV float sigf(float x) { return 1.f / (1.f + expf(-x)); }

#if defined(__has_builtin)
#if __has_builtin(__builtin_amdgcn_global_load_lds)
#define HAVE_GLL 1
#endif
#if __has_builtin(__builtin_amdgcn_fdot2)
#define HAVE_FDOT2 1
#endif
#endif

DEV float dot2f(unsigned a, unsigned b, float c) {
#if HAVE_FDOT2
    return __builtin_amdgcn_fdot2(__builtin_bit_cast(f16x2, a),
                                  __builtin_bit_cast(f16x2, b), c, false);
#else
    f16x2 av = __builtin_bit_cast(f16x2, a);
    f16x2 bv = __builtin_bit_cast(f16x2, b);
    return c + (float)av.x * (float)bv.x + (float)av.y * (float)bv.y;
#endif
}

// relaxed agent-scope = plain sc1 loads/stores (MALL-coherent, no wbl2/inv)
DEV u64t ld_u64_cg(const u64t* p) {
    return __hip_atomic_load(p, __ATOMIC_RELAXED, __HIP_MEMORY_SCOPE_AGENT);
}
DEV unsigned ld_u32_cg(const unsigned* p) {
    return __hip_atomic_load(p, __ATOMIC_RELAXED, __HIP_MEMORY_SCOPE_AGENT);
}
DEV void st_u32_cg(unsigned* p, unsigned v) {
    __hip_atomic_store(p, v, __ATOMIC_RELAXED, __HIP_MEMORY_SCOPE_AGENT);
}

#if HAVE_GLL
DEV void gll16(f16* lds, const f16* g) {
    __builtin_amdgcn_global_load_lds(
        (const __attribute__((address_space(1))) void*)g,
        (__attribute__((address_space(3))) void*)lds, 16, 0, 0);
}
#endif

DEV unsigned pkh2(float a, float b) {
    f16x2 h = {(f16)a, (f16)b};
    return __builtin_bit_cast(unsigned, h);
}

// ---------------- converts / packing ----------------

__global__ __launch_bounds__(256) void cvt_f16(const float* __restrict__ s,
                                               f16* __restrict__ d, int n4) {
    for (int i = blockIdx.x * blockDim.x + threadIdx.x; i < n4;
         i += gridDim.x * blockDim.x) {
        float4 v = ((const float4*)s)[i];
        f16x4 o = {(f16)v.x, (f16)v.y, (f16)v.z, (f16)v.w};
        ((f16x4*)d)[i] = o;
    }
}

// Pack W_hh [2048][512] f32 into MFMA B-fragment order, f16 (R6 layout).
__global__ __launch_bounds__(256) void pack_wfrag(const float* __restrict__ W,
                                                  f16* __restrict__ Wf) {
    int id = blockIdx.x * 256 + threadIdx.x;  // 2^17 total
    if (id >= NBLK * 2 * 16 * 64) return;
    int lane = id & 63;
    int ks = (id >> 6) & 15;
    int ni = (id >> 10) & 1;
    int n = id >> 11;
    int cl = ni * 16 + (lane & 15);
    int ul = cl >> 2, g = cl & 3;
    int unit = n * 8 + ul;
    int k = ks * 32 + (lane >> 4) * 8;
    const float* src = W + (size_t)(g * 512 + unit) * 512 + k;
    float4 a = *(const float4*)src;
    float4 b = *(const float4*)(src + 4);
    f16x8 o = {(f16)a.x, (f16)a.y, (f16)a.z, (f16)a.w,
               (f16)b.x, (f16)b.y, (f16)b.z, (f16)b.w};
    *(f16x8*)(Wf + (size_t)id * 8) = o;
}

// wattP4 uint4[k8 (64)][j (1024)] : 4 packed f16-pairs of W_att[j][k8*8 ..+8)
__global__ __launch_bounds__(256) void pack_watt4(const float* __restrict__ W,
                                                  uint4* __restrict__ P) {
    int id = blockIdx.x * 256 + threadIdx.x;
    if (id >= 64 * 1024) return;
    int j = id & 1023, k8 = id >> 10;
    const float* src = W + (size_t)j * 512 + k8 * 8;
    float4 a = *(const float4*)src;
    float4 b = *(const float4*)(src + 4);
    uint4 o = {pkh2(a.x, a.y), pkh2(a.z, a.w), pkh2(b.x, b.y), pkh2(b.z, b.w)};
    P[(size_t)k8 * 1024 + j] = o;
}

// wcombP4 uint4[k8 (192)][j (512)] : pairs of W_comb[j][k8*8 ..+8)
__global__ __launch_bounds__(256) void pack_wcomb4(const float* __restrict__ W,
                                                   uint4* __restrict__ P) {
    int id = blockIdx.x * 256 + threadIdx.x;
    if (id >= 192 * 512) return;
    int j = id & 511, k8 = id >> 9;
    const float* src = W + (size_t)j * 1536 + k8 * 8;
    float4 a = *(const float4*)src;
    float4 b = *(const float4*)(src + 4);
    uint4 o = {pkh2(a.x, a.y), pkh2(a.z, a.w), pkh2(b.x, b.y), pkh2(b.z, b.w)};
    P[(size_t)k8 * 512 + j] = o;
}

// x[bt][e] = (f16) emb[tok[bt]][e]
__global__ __launch_bounds__(256) void gather_x(const int* __restrict__ tok,
                                                const float* __restrict__ emb,
                                                f16* __restrict__ x) {
    int id = blockIdx.x * blockDim.x + threadIdx.x;  // 2048*128
    if (id >= BT * (E / 4)) return;
    int row = id >> 7;
    int e4 = (id & 127) * 4;
    int t = tok[row];
    float4 v = *(const float4*)(emb + (size_t)t * E + e4);
    f16x4 o = {(f16)v.x, (f16)v.y, (f16)v.z, (f16)v.w};
    ((f16x4*)x)[id] = o;
}

// stage h0 into xbuf[0] (block-major) and reset flags/oflags (replay safe)
__global__ __launch_bounds__(256) void init_h0(const float* __restrict__ h0,
                                               f16* __restrict__ xbuf,
                                               unsigned* __restrict__ fl,
                                               unsigned* __restrict__ ofl) {
    int i = blockIdx.x * 256 + threadIdx.x;  // 64 blocks -> 16384
    if (i < B * H) {
        int nn = i >> 8;
        int bb = (i >> 3) & 31;
        int ul = i & 7;
        xbuf[i] = (f16)h0[bb * 512 + nn * 8 + ul];
    }
    if (i < NBLK) fl[i] = 0u;
    if (i < NFEED) ofl[i] = 0u;
}

// ---------------- gates GEMM (proven; PERM output layout) ----------------

template <bool BIAS, bool B2, bool PERM, typename OUT>
__global__ __launch_bounds__(256) void gemm_bt(
    const f16* __restrict__ A, int lda, const f16* __restrict__ W, int ldw,
    OUT* __restrict__ C, int ldc, int K, const float* __restrict__ bias1,
    const float* __restrict__ bias2) {
    __shared__ f16 smA[128 * 32];
    __shared__ f16 smB[128 * 32];
    const int tid = threadIdx.x;
    const int lane = tid & 63;
    const int wv = tid >> 6;
    const int wr = wv >> 1, wc = wv & 1;
    const int m0 = blockIdx.y * 128, n0 = blockIdx.x * 128;
    const int ar0 = tid >> 2;
    const int kq = (tid & 3) * 8;

    f32x4 acc[4][4];
#pragma unroll
    for (int m = 0; m < 4; m++)
#pragma unroll
        for (int n = 0; n < 4; n++) acc[m][n] = {0.f, 0.f, 0.f, 0.f};

    const int arow = wr * 64 + (lane & 15);
    const int brow = wc * 64 + (lane & 15);
    const int kk = (lane >> 4) * 8;

    const int ksteps = K >> 5;
    for (int s = 0; s < ksteps; ++s) {
        const int k0 = s * 32;
        const f16* Ag = A + (size_t)(m0 + ar0) * lda + k0 + kq;
        const f16* Wg = W + (size_t)(n0 + ar0) * ldw + k0 + kq;
#if HAVE_GLL
        __syncthreads();
        gll16(smA + wv * 512, Ag);
        gll16(smA + 2048 + wv * 512, Ag + (size_t)64 * lda);
        gll16(smB + wv * 512, Wg);
        gll16(smB + 2048 + wv * 512, Wg + (size_t)64 * ldw);
        __syncthreads();
#else
        uint4 va0 = *(const uint4*)Ag;
        uint4 va1 = *(const uint4*)(Ag + (size_t)64 * lda);
        uint4 vb0 = *(const uint4*)Wg;
        uint4 vb1 = *(const uint4*)(Wg + (size_t)64 * ldw);
        __syncthreads();
        *(uint4*)(smA + tid * 8) = va0;
        *(uint4*)(smA + (tid + 256) * 8) = va1;
        *(uint4*)(smB + tid * 8) = vb0;
        *(uint4*)(smB + (tid + 256) * 8) = vb1;
        __syncthreads();
#endif
        f16x8 af[4], bfr[4];
#pragma unroll
        for (int m = 0; m < 4; m++)
            af[m] = *(const f16x8*)(smA + (arow + m * 16) * 32 + kk);
#pragma unroll
        for (int n = 0; n < 4; n++)
            bfr[n] = *(const f16x8*)(smB + (brow + n * 16) * 32 + kk);
#pragma unroll
        for (int m = 0; m < 4; m++)
#pragma unroll
            for (int n = 0; n < 4; n++)
                acc[m][n] = __builtin_amdgcn_mfma_f32_16x16x32_f16(
                    af[m], bfr[n], acc[m][n], 0, 0, 0);
    }

    const int fr = lane & 15, fq = lane >> 4;
#pragma unroll
    for (int m = 0; m < 4; m++) {
        const int row0 = m0 + wr * 64 + m * 16 + fq * 4;
#pragma unroll
        for (int n = 0; n < 4; n++) {
            const int col = n0 + wc * 64 + n * 16 + fr;
            float bb = 0.f;
            if (BIAS) bb += bias1[col];
            if (B2) bb += bias2[col];
            int nb = 0, cl = 0;
            if (PERM) {
                int g = col >> 9;
                int unit = col & 511;
                nb = unit >> 3;
                cl = ((unit & 7) << 2) | g;
            }
#pragma unroll
            for (int r = 0; r < 4; r++) {
                float v = acc[m][n][r] + bb;
                if (PERM) {
                    int bt = row0 + r;
                    int b_ = bt >> 6, tt = bt & 63;
                    C[((size_t)(tt * 64 + nb) * 32 + b_) * 32 + cl] = (OUT)v;
                } else {
                    C[(size_t)(row0 + r) * ldc + col] = (OUT)v;
                }
            }
        }
    }
}

// ---------------- MEGA: scan (0-63) + chunked feeders (64-95) + consumers --
// Scan: R14-verified. hseq(t) valid when all flags >= t+2 (vmcnt-drain rule);
//   epilogue publishes 66.
// Feeders (1/batch): per 8-step chunk g, wait flags >= 8g+9, load 8 h vectors
//   into LDS, apply every weight load to all 8 timesteps (8x amortization ->
//   ~16us/chunk < 32us scan cadence). Publish oflag[b] = 8g+8.
// Consumers (160): per chunk g, wait oflags >= 8g+8, stage A (128 rows of
//   outs, mh = cc&1 constant) ONCE, then 3-4 proven 128x128 MFMA tiles
//   (W_out via global_load_lds cached path). One-way chain, all co-resident.

constexpr int LDS_BYTES = 141312;

__global__ __launch_bounds__(256, 1) void mega(
    const float* __restrict__ gxp, const f16* __restrict__ Wfrag,
    const float* __restrict__ c0, f16* __restrict__ xbuf,
    unsigned* __restrict__ flags, f16* __restrict__ hseq,
    float* __restrict__ hout, float* __restrict__ cout,
    const uint4* __restrict__ wattQ, const f16* __restrict__ enc_h,
    const uint4* __restrict__ wcombQ, const float* __restrict__ b_comb,
    f16* __restrict__ outsP, unsigned* __restrict__ oflag,
    const f16* __restrict__ W_out_h, const float* __restrict__ b_out,
    float* __restrict__ logits) {
    __shared__ __align__(16) char lds[LDS_BYTES];
    const int bid = blockIdx.x;
    const int tid = threadIdx.x;
    const int lane = tid & 63, wv = tid >> 6;

    if (bid < NBLK) {
        // ================= SCAN (R14-verified) =================
        const int n = bid;
        const int mi = wv >> 1, ni = wv & 1;
        f16(*hst)[520] = (f16(*)[520])lds;
        float(*gl)[32] = (float(*)[32])(lds + 33280);

        f16x8 bf[16];
        const f16* wbase =
            Wfrag + (size_t)((n * 2 + ni) * 16) * 512 + lane * 8;
#pragma unroll
        for (int ks = 0; ks < 16; ks++)
            bf[ks] = *(const f16x8*)(wbase + ks * 512);

        const int bb = tid >> 3, ul = tid & 7;
        const int unit = n * 8 + ul;
        float c = c0[bb * 512 + unit];
        float h = 0.f;

        const int sb = (tid & 63) >> 1;
        const int su0 = (tid & 1) * 4;
        const int arow = mi * 16 + (lane & 15);
        const int kcol0 = (lane >> 4) * 8;
        const int fr = lane & 15, fq = lane >> 4;

        for (int t = 0; t < T; ++t) {
            float4 gx4 = *(const float4*)(gxp +
                ((size_t)(t * NBLK + n) * 32 + bb) * 32 + ul * 4);
            for (;;) {
                unsigned v = ld_u32_cg(flags + lane);
                if (__all(v >= (unsigned)t)) break;
                __builtin_amdgcn_s_sleep(1);
            }
            asm volatile("" ::: "memory");
            const u64t* src = (const u64t*)(xbuf + (t & 1) * (B * H));
            u64t v[16];
#pragma unroll
            for (int i = 0; i < 16; i++) v[i] = ld_u64_cg(src + i * 256 + tid);
#pragma unroll
            for (int i = 0; i < 16; i++) {
                int np = i * 4 + wv;
                *(u64t*)(&hst[sb][np * 8 + su0]) = v[i];
            }
            __syncthreads();
            f32x4 acc0 = {0.f, 0.f, 0.f, 0.f}, acc1 = {0.f, 0.f, 0.f, 0.f};
#pragma unroll
            for (int ks = 0; ks < 16; ks++) {
                f16x8 af = *(const f16x8*)(&hst[arow][ks * 32 + kcol0]);
                if (ks & 1)
                    acc1 = __builtin_amdgcn_mfma_f32_16x16x32_f16(af, bf[ks],
                                                                  acc1, 0, 0, 0);
                else
                    acc0 = __builtin_amdgcn_mfma_f32_16x16x32_f16(af, bf[ks],
                                                                  acc0, 0, 0, 0);
            }
#pragma unroll
            for (int r = 0; r < 4; r++)
                gl[mi * 16 + fq * 4 + r][ni * 16 + fr] = acc0[r] + acc1[r];
            __syncthreads();
            float4 gv = *(const float4*)&gl[bb][ul * 4];
            float gi = gv.x + gx4.x;
            float gf = gv.y + gx4.y;
            float gg = gv.z + gx4.z;
            float go = gv.w + gx4.w;
            c = sigf(gf) * c + sigf(gi) * tanhf(gg);
            h = sigf(go) * tanhf(c);
            f16 hh = (f16)h;
            unsigned hv = (unsigned)__builtin_bit_cast(unsigned short, hh);
            unsigned other = (unsigned)__shfl_xor((int)hv, 1);
            unsigned packed = hv | (other << 16);
            f16* xn = xbuf + ((t + 1) & 1) * (B * H);
            if ((ul & 1) == 0)
                st_u32_cg((unsigned*)(xn + n * 256 + bb * 8 + ul), packed);
            if (t < T - 1) {
                asm volatile("s_waitcnt vmcnt(0)" ::: "memory");
                __syncthreads();
                if (tid == 0) st_u32_cg(flags + n, (unsigned)(t + 1));
            } else {
                __syncthreads();
            }
            if ((ul & 1) == 0)
                st_u32_cg((unsigned*)(hseq + ((size_t)t * 32 + bb) * 512 +
                                      unit), packed);
        }
        asm volatile("s_waitcnt vmcnt(0)" ::: "memory");
        __syncthreads();
        if (tid == 0) st_u32_cg(flags + n, 66u);
        hout[bb * 512 + unit] = h;
        cout[bb * 512 + unit] = c;

    } else if (bid < NBLK + NFEED) {
        // ========== FEEDER (one batch b), 8-step chunks ==========
        const int b = bid - NBLK;
        unsigned(*hch)[256] = (unsigned(*)[256])lds;        // 8KB
        f16(*qch)[1024] = (f16(*)[1024])(lds + 8192);       // 16KB
        float(*wsch)[64] = (float(*)[64])(lds + 24576);     // 2KB
        f16(*apch)[1024] = (f16(*)[1024])(lds + 26624);     // 16KB
        const unsigned* hseqU = (const unsigned*)hseq;
        unsigned* outsU = (unsigned*)outsP;

        for (int g = 0; g < 8; ++g) {
            const unsigned target = (unsigned)(g * 8 + 9);
            for (;;) {
                unsigned v = ld_u32_cg(flags + lane);
                if (__all(v >= target)) break;
                __builtin_amdgcn_s_sleep(4);
            }
            asm volatile("" ::: "memory");
#pragma unroll
            for (int i = 0; i < 8; ++i)
                hch[i][tid] = ld_u32_cg(
                    hseqU + ((size_t)(g * 8 + i) * 32 + b) * 256 + tid);
            __syncthreads();
            // ---- q: 4 cols/thread x 8 t (weights amortized 8x) ----
            {
                float q0[8], q1[8], q2[8], q3[8];
#pragma unroll
                for (int i = 0; i < 8; ++i) {
                    q0[i] = 0.f; q1[i] = 0.f; q2[i] = 0.f; q3[i] = 0.f;
                }
                for (int k8 = 0; k8 < 64; ++k8) {
                    uint4 w0 = wattQ[(size_t)k8 * 1024 + tid];
                    uint4 w1 = wattQ[(size_t)k8 * 1024 + tid + 256];
                    uint4 w2 = wattQ[(size_t)k8 * 1024 + tid + 512];
                    uint4 w3 = wattQ[(size_t)k8 * 1024 + tid + 768];
#pragma unroll
                    for (int i = 0; i < 8; ++i) {
                        uint4 hh = *(const uint4*)&hch[i][k8 * 4];
                        q0[i] = dot2f(hh.x, w0.x, q0[i]);
                        q0[i] = dot2f(hh.y, w0.y, q0[i]);
                        q0[i] = dot2f(hh.z, w0.z, q0[i]);
                        q0[i] = dot2f(hh.w, w0.w, q0[i]);
                        q1[i] = dot2f(hh.x, w1.x, q1[i]);
                        q1[i] = dot2f(hh.y, w1.y, q1[i]);
                        q1[i] = dot2f(hh.z, w1.z, q1[i]);
                        q1[i] = dot2f(hh.w, w1.w, q1[i]);
                        q2[i] = dot2f(hh.x, w2.x, q2[i]);
                        q2[i] = dot2f(hh.y, w2.y, q2[i]);
                        q2[i] = dot2f(hh.z, w2.z, q2[i]);
                        q2[i] = dot2f(hh.w, w2.w, q2[i]);
                        q3[i] = dot2f(hh.x, w3.x, q3[i]);
                        q3[i] = dot2f(hh.y, w3.y, q3[i]);
                        q3[i] = dot2f(hh.z, w3.z, q3[i]);
                        q3[i] = dot2f(hh.w, w3.w, q3[i]);
                    }
                }
#pragma unroll
                for (int i = 0; i < 8; ++i) {
                    qch[i][tid] = (f16)q0[i];
                    qch[i][tid + 256] = (f16)q1[i];
                    qch[i][tid + 512] = (f16)q2[i];
                    qch[i][tid + 768] = (f16)q3[i];
                }
            }
            __syncthreads();
            // ---- w[s] = q . enc[b][s], 4 threads/s, 8 t ----
            {
                int s = tid >> 2, part = tid & 3;
                const unsigned* encp =
                    (const unsigned*)enc_h + ((size_t)(b * 64 + s)) * 512 +
                    part * 128;
                float wa[8];
#pragma unroll
                for (int i = 0; i < 8; ++i) wa[i] = 0.f;
                for (int it = 0; it < 32; ++it) {
                    uint4 e4 = *(const uint4*)&encp[it * 4];
#pragma unroll
                    for (int i = 0; i < 8; ++i) {
                        const unsigned* qp =
                            (const unsigned*)&qch[i][0] + part * 128;
                        uint4 q4 = *(const uint4*)&qp[it * 4];
                        wa[i] = dot2f(q4.x, e4.x, wa[i]);
                        wa[i] = dot2f(q4.y, e4.y, wa[i]);
                        wa[i] = dot2f(q4.z, e4.z, wa[i]);
                        wa[i] = dot2f(q4.w, e4.w, wa[i]);
                    }
                }
#pragma unroll
                for (int i = 0; i < 8; ++i) {
                    float w = wa[i];
                    w += __shfl_xor(w, 1);
                    w += __shfl_xor(w, 2);
                    if (part == 0) wsch[i][s] = w;
                }
            }
            __syncthreads();
            // ---- applied: 4 d/thread, 8 t (enc amortized 8x) ----
            {
                float a0[8], a1[8], a2[8], a3[8];
#pragma unroll
                for (int i = 0; i < 8; ++i) {
                    a0[i] = 0.f; a1[i] = 0.f; a2[i] = 0.f; a3[i] = 0.f;
                }
                for (int s2 = 0; s2 < 64; ++s2) {
                    const f16* er =
                        enc_h + ((size_t)(b * 64 + s2)) * 1024 + tid;
                    float e0 = (float)er[0];
                    float e1 = (float)er[256];
                    float e2 = (float)er[512];
                    float e3 = (float)er[768];
#pragma unroll
                    for (int i = 0; i < 8; ++i) {
                        float w = wsch[i][s2];
                        a0[i] += w * e0;
                        a1[i] += w * e1;
                        a2[i] += w * e2;
                        a3[i] += w * e3;
                    }
                }
#pragma unroll
                for (int i = 0; i < 8; ++i) {
                    apch[i][tid] = (f16)a0[i];
                    apch[i][tid + 256] = (f16)a1[i];
                    apch[i][tid + 512] = (f16)a2[i];
                    apch[i][tid + 768] = (f16)a3[i];
                }
            }
            __syncthreads();
            // ---- outs: 2 cols/thread x 8 t ----
            {
                float o0[8], o1[8];
#pragma unroll
                for (int i = 0; i < 8; ++i) { o0[i] = 0.f; o1[i] = 0.f; }
                for (int k8 = 0; k8 < 64; ++k8) {
                    uint4 w0 = wcombQ[(size_t)k8 * 512 + tid];
                    uint4 w1 = wcombQ[(size_t)k8 * 512 + tid + 256];
#pragma unroll
                    for (int i = 0; i < 8; ++i) {
                        uint4 hh = *(const uint4*)&hch[i][k8 * 4];
                        o0[i] = dot2f(hh.x, w0.x, o0[i]);
                        o0[i] = dot2f(hh.y, w0.y, o0[i]);
                        o0[i] = dot2f(hh.z, w0.z, o0[i]);
                        o0[i] = dot2f(hh.w, w0.w, o0[i]);
                        o1[i] = dot2f(hh.x, w1.x, o1[i]);
                        o1[i] = dot2f(hh.y, w1.y, o1[i]);
                        o1[i] = dot2f(hh.z, w1.z, o1[i]);
                        o1[i] = dot2f(hh.w, w1.w, o1[i]);
                    }
                }
                for (int k8 = 0; k8 < 128; ++k8) {
                    uint4 w0 = wcombQ[(size_t)(64 + k8) * 512 + tid];
                    uint4 w1 = wcombQ[(size_t)(64 + k8) * 512 + tid + 256];
#pragma unroll
                    for (int i = 0; i < 8; ++i) {
                        uint4 aa = *(const uint4*)((const unsigned*)&apch[i][0] +
                                                   k8 * 4);
                        o0[i] = dot2f(aa.x, w0.x, o0[i]);
                        o0[i] = dot2f(aa.y, w0.y, o0[i]);
                        o0[i] = dot2f(aa.z, w0.z, o0[i]);
                        o0[i] = dot2f(aa.w, w0.w, o0[i]);
                        o1[i] = dot2f(aa.x, w1.x, o1[i]);
                        o1[i] = dot2f(aa.y, w1.y, o1[i]);
                        o1[i] = dot2f(aa.z, w1.z, o1[i]);
                        o1[i] = dot2f(aa.w, w1.w, o1[i]);
                    }
                }
                float bc0 = b_comb[tid];
                float bc1 = b_comb[tid + 256];
#pragma unroll
                for (int i = 0; i < 8; ++i) {
                    float v0 = tanhf(o0[i] + bc0);
                    float v1 = tanhf(o1[i] + bc1);
                    unsigned p0 = (unsigned)__builtin_bit_cast(unsigned short,
                                                               (f16)v0);
                    unsigned p1 = (unsigned)__builtin_bit_cast(unsigned short,
                                                               (f16)v1);
                    unsigned s0 = (unsigned)__shfl_xor((int)p0, 1);
                    unsigned s1 = (unsigned)__shfl_xor((int)p1, 1);
                    if ((tid & 1) == 0) {
                        // bt-major: outs[(b*64 + 8g+i)][512] f16 = 256 u32
                        size_t base = ((size_t)(b * 64 + g * 8 + i)) * 256;
                        st_u32_cg(outsU + base + (tid >> 1), p0 | (s0 << 16));
                        st_u32_cg(outsU + base + 128 + (tid >> 1),
                                  p1 | (s1 << 16));
                    }
                }
            }
            asm volatile("s_waitcnt vmcnt(0)" ::: "memory");
            __syncthreads();
            if (tid == 0) st_u32_cg(oflag + b, (unsigned)(g * 8 + 8));
        }

    } else {
        // ========== LOGITS CONSUMER (chunked, A staged once/chunk) ==========
        const int cc = bid - NBLK - NFEED;  // 0..159
        f16(*smA)[520] = (f16(*)[520])lds;           // 133120 B
        f16* smB = (f16*)(lds + 133120);             // 8192 B
        const int wr = wv >> 1, wc = wv & 1;
        const int ar0 = tid >> 2;
        const int kq = (tid & 3) * 8;
        const int fr = lane & 15, fq = lane >> 4;
        const int kk = (lane >> 4) * 8;
        const int mh = cc & 1;  // NCONS even -> constant per block

        for (int g = 0; g < 8; ++g) {
            const unsigned target = (unsigned)(g * 8 + 8);
            for (;;) {
                unsigned v = ld_u32_cg(oflag + (lane & 31));
                if (__all(v >= target)) break;
                __builtin_amdgcn_s_sleep(16);
            }
            asm volatile("" ::: "memory");
            __syncthreads();  // prior chunk's smA reads done
            // stage A ONCE per chunk: 128 rows (bt-major outs)
            {
                int r = tid >> 1, hf2 = tid & 1;
                int bA = (mh * 128 + r) >> 3;
                int tA = g * 8 + (r & 7);
                const u64t* srcA = (const u64t*)outsP +
                                   ((size_t)(bA * 64 + tA)) * 128 + hf2 * 64;
#pragma unroll
                for (int j = 0; j < 2; ++j) {
                    u64t a[32];
#pragma unroll
                    for (int i = 0; i < 32; ++i)
                        a[i] = ld_u64_cg(srcA + j * 32 + i);
#pragma unroll
                    for (int i = 0; i < 32; ++i)
                        *(u64t*)(&smA[r][hf2 * 256 + j * 128 + i * 4]) = a[i];
                }
            }
            __syncthreads();
            for (int tix = cc; tix < 500; tix += NCONS) {
                const int p = tix >> 1;
                f32x4 acc[4][4];
#pragma unroll
                for (int m = 0; m < 4; m++)
#pragma unroll
                    for (int nn = 0; nn < 4; nn++)
                        acc[m][nn] = {0.f, 0.f, 0.f, 0.f};
                for (int s = 0; s < 16; ++s) {
                    const f16* Wg = W_out_h +
                                    (size_t)(p * 128 + ar0) * 512 + s * 32 + kq;
                    __syncthreads();  // prev smB reads done
#if HAVE_GLL
                    gll16(smB + wv * 512, Wg);
                    gll16(smB + 2048 + wv * 512, Wg + (size_t)64 * 512);
#else
                    uint4 vb0 = *(const uint4*)Wg;
                    uint4 vb1 = *(const uint4*)(Wg + (size_t)64 * 512);
                    *(uint4*)(smB + tid * 8) = vb0;
                    *(uint4*)(smB + (tid + 256) * 8) = vb1;
#endif
                    __syncthreads();
                    f16x8 af[4], bfr[4];
#pragma unroll
                    for (int m = 0; m < 4; m++)
                        af[m] = *(const f16x8*)(&smA[wr * 64 + m * 16 + fr]
                                                    [s * 32 + kk]);
#pragma unroll
                    for (int nn = 0; nn < 4; nn++)
                        bfr[nn] = *(const f16x8*)(smB +
                                                  (wc * 64 + nn * 16 + fr) * 32 +
                                                  kk);
#pragma unroll
                    for (int m = 0; m < 4; m++)
#pragma unroll
                        for (int nn = 0; nn < 4; nn++)
                            acc[m][nn] = __builtin_amdgcn_mfma_f32_16x16x32_f16(
                                af[m], bfr[nn], acc[m][nn], 0, 0, 0);
                }
#pragma unroll
                for (int m = 0; m < 4; m++) {
                    const int row0 = wr * 64 + m * 16 + fq * 4;
#pragma unroll
                    for (int nn = 0; nn < 4; nn++) {
                        const int col = p * 128 + wc * 64 + nn * 16 + fr;
                        const float bo = b_out[col];
#pragma unroll
                        for (int r = 0; r < 4; r++) {
                            int rowT = mh * 128 + row0 + r;
                            int bC = rowT >> 3;
                            int btC = bC * 64 + g * 8 + (rowT & 7);
                            logits[(size_t)btC * 32000 + col] =
                                acc[m][nn][r] + bo;
                        }
                    }
                }
            }
        }
    }
}

// ---------------- launcher ----------------

extern "C" void kernel_launch(void* const* d_in, const int* in_sizes, int n_in,
                              void* d_out, int out_size, void* d_ws,
                              size_t ws_size, hipStream_t stream) {
    const int* tok = (const int*)d_in[0];
    const float* enc = (const float*)d_in[1];
    const float* h0 = (const float*)d_in[2];
    const float* c0 = (const float*)d_in[3];
    const float* emb = (const float*)d_in[4];
    const float* W_ih = (const float*)d_in[5];
    const float* W_hh = (const float*)d_in[6];
    const float* b_ih = (const float*)d_in[7];
    const float* b_hh = (const float*)d_in[8];
    const float* W_att = (const float*)d_in[9];
    const float* W_comb = (const float*)d_in[10];
    const float* b_comb = (const float*)d_in[11];
    const float* W_out = (const float*)d_in[12];
    const float* b_out = (const float*)d_in[13];

    float* out_logits = (float*)d_out;
    float* out_h = out_logits + (size_t)BT * V;
    float* out_c = out_h + (size_t)B * H;

    char* p = (char*)d_ws;
    auto alloc = [&](size_t bytes) -> void* {
        void* r = (void*)p;
        p += (bytes + 255) & ~(size_t)255;
        return r;
    };
    f16* W_ih_h = (f16*)alloc((size_t)G4 * E * 2);           // 2MB
    f16* Wfrag = (f16*)alloc((size_t)NBLK * 2 * 16 * 64 * 8 * 2);  // 2MB
    f16* W_out_h = (f16*)alloc((size_t)V * 512 * 2);         // 32MB
    f16* enc_h = (f16*)alloc((size_t)B * S * 1024 * 2);      // 4MB
    uint4* wattQ = (uint4*)alloc((size_t)64 * 1024 * 16);    // 1MB
    uint4* wcombQ = (uint4*)alloc((size_t)192 * 512 * 16);   // 1.5MB
    f16* x_h = (f16*)alloc((size_t)BT * E * 2);              // 2MB
    float* gxp = (float*)alloc((size_t)T * NBLK * 32 * 32 * 4);  // 16MB
    f16* hseq = (f16*)alloc((size_t)T * B * 512 * 2);        // 2MB
    f16* outsP = (f16*)alloc((size_t)BT * 512 * 2);          // 2MB (bt-major)
    f16* xbuf = (f16*)alloc((size_t)2 * B * H * 2);          // 128KB
    unsigned* flags = (unsigned*)alloc(256);
    unsigned* oflag = (unsigned*)alloc(256);

    cvt_f16<<<512, 256, 0, stream>>>(W_ih, W_ih_h, G4 * E / 4);
    cvt_f16<<<2048, 256, 0, stream>>>(W_out, W_out_h, V * 512 / 4);
    cvt_f16<<<1024, 256, 0, stream>>>(enc, enc_h, B * S * 1024 / 4);
    pack_wfrag<<<512, 256, 0, stream>>>(W_hh, Wfrag);
    pack_watt4<<<256, 256, 0, stream>>>(W_att, wattQ);
    pack_wcomb4<<<384, 256, 0, stream>>>(W_comb, wcombQ);
    gather_x<<<1024, 256, 0, stream>>>(tok, emb, x_h);
    init_h0<<<64, 256, 0, stream>>>(h0, xbuf, flags, oflag);

    // gates_x = x @ W_ih^T + b_ih + b_hh, permuted for the scan
    gemm_bt<true, true, true, float><<<dim3(16, 16), 256, 0, stream>>>(
        x_h, E, W_ih_h, E, gxp, 0, E, b_ih, b_hh);

    // fused scan + chunked attention feeders + chunked logits consumers
    mega<<<NBLK + NFEED + NCONS, 256, 0, stream>>>(
        gxp, Wfrag, c0, xbuf, flags, hseq, out_h, out_c, wattQ, enc_h, wcombQ,
        b_comb, outsP, oflag, W_out_h, b_out, out_logits);
}

// Round 16
// 1030.194 us; speedup vs baseline: 2.1879x; 1.2185x over previous
//
#include <hip/hip_runtime.h>
#include <hip/hip_fp16.h>

typedef _Float16 f16;
typedef _Float16 f16x2 __attribute__((ext_vector_type(2)));
typedef _Float16 f16x4 __attribute__((ext_vector_type(4)));
typedef _Float16 f16x8 __attribute__((ext_vector_type(8)));
typedef float    f32x4 __attribute__((ext_vector_type(4)));
typedef unsigned long long u64t;

#define DEV __device__ __forceinline__

constexpr int B = 32, T = 64, S = 64, H = 512, E = 512, V = 32000;
constexpr int BT = B * T;      // 2048
constexpr int G4 = 4 * H;      // 2048
constexpr int NBLK = 64;       // scan blocks
constexpr int NFEED = 32;      // feeder blocks (1 per batch)

DEV float sigf(float x) { return 1.f / (1.f + expf(-x)); }

#if defined(__has_builtin)
#if __has_builtin(__builtin_amdgcn_global_load_lds)
#define HAVE_GLL 1
#endif
#if __has_builtin(__builtin_amdgcn_fdot2)
#define HAVE_FDOT2 1
#endif
#endif

DEV float dot2f(unsigned a, unsigned b, float c) {
#if HAVE_FDOT2
    return __builtin_amdgcn_fdot2(__builtin_bit_cast(f16x2, a),
                                  __builtin_bit_cast(f16x2, b), c, false);
#else
    f16x2 av = __builtin_bit_cast(f16x2, a);
    f16x2 bv = __builtin_bit_cast(f16x2, b);
    return c + (float)av.x * (float)bv.x + (float)av.y * (float)bv.y;
#endif
}

// relaxed agent-scope = plain sc1 loads/stores (MALL-coherent, no wbl2/inv)
DEV u64t ld_u64_cg(const u64t* p) {
    return __hip_atomic_load(p, __ATOMIC_RELAXED, __HIP_MEMORY_SCOPE_AGENT);
}
DEV unsigned ld_u32_cg(const unsigned* p) {
    return __hip_atomic_load(p, __ATOMIC_RELAXED, __HIP_MEMORY_SCOPE_AGENT);
}
DEV void st_u32_cg(unsigned* p, unsigned v) {
    __hip_atomic_store(p, v, __ATOMIC_RELAXED, __HIP_MEMORY_SCOPE_AGENT);
}

#if HAVE_GLL
DEV void gll16(f16* lds, const f16* g) {
    __builtin_amdgcn_global_load_lds(
        (const __attribute__((address_space(1))) void*)g,
        (__attribute__((address_space(3))) void*)lds, 16, 0, 0);
}
#endif

DEV unsigned pkh2(float a, float b) {
    f16x2 h = {(f16)a, (f16)b};
    return __builtin_bit_cast(unsigned, h);
}

// ---------------- W_out convert (big, grid-stride) ----------------

__global__ __launch_bounds__(256) void cvt_f16(const float* __restrict__ s,
                                               f16* __restrict__ d, int n4) {
    for (int i = blockIdx.x * blockDim.x + threadIdx.x; i < n4;
         i += gridDim.x * blockDim.x) {
        float4 v = ((const float4*)s)[i];
        f16x4 o = {(f16)v.x, (f16)v.y, (f16)v.z, (f16)v.w};
        ((f16x4*)d)[i] = o;
    }
}

// ---------------- fused prep: all small converts/packs, exact ranges -------
// [0,1024)    cvt W_ih      (262144 float4)
// [1024,3072) cvt enc       (524288 float4)
// [3072,3584) pack_wfrag    (131072 items)
// [3584,3840) pack_watt4    (65536 items)
// [3840,4224) pack_wcomb4   (98304 items)
// [4224,5248) gather_x      (262144 items)
// [5248,5312) init_h0+flags (16384 items)

__global__ __launch_bounds__(256) void prep_all(
    const float* __restrict__ W_ih, f16* __restrict__ W_ih_h,
    const float* __restrict__ enc, f16* __restrict__ enc_h,
    const float* __restrict__ W_hh, f16* __restrict__ Wfrag,
    const float* __restrict__ W_att, uint4* __restrict__ wattQ,
    const float* __restrict__ W_comb, uint4* __restrict__ wcombQ,
    const int* __restrict__ tok, const float* __restrict__ emb,
    f16* __restrict__ x_h, const float* __restrict__ h0,
    f16* __restrict__ xbuf, unsigned* __restrict__ flags) {
    const int bid = blockIdx.x;
    const int tid = threadIdx.x;
    if (bid < 1024) {
        int i = bid * 256 + tid;
        float4 v = ((const float4*)W_ih)[i];
        f16x4 o = {(f16)v.x, (f16)v.y, (f16)v.z, (f16)v.w};
        ((f16x4*)W_ih_h)[i] = o;
    } else if (bid < 3072) {
        int i = (bid - 1024) * 256 + tid;
        float4 v = ((const float4*)enc)[i];
        f16x4 o = {(f16)v.x, (f16)v.y, (f16)v.z, (f16)v.w};
        ((f16x4*)enc_h)[i] = o;
    } else if (bid < 3584) {
        int id = (bid - 3072) * 256 + tid;  // R6-verified pack_wfrag body
        int lane = id & 63;
        int ks = (id >> 6) & 15;
        int ni = (id >> 10) & 1;
        int n = id >> 11;
        int cl = ni * 16 + (lane & 15);
        int ul = cl >> 2, g = cl & 3;
        int unit = n * 8 + ul;
        int k = ks * 32 + (lane >> 4) * 8;
        const float* src = W_hh + (size_t)(g * 512 + unit) * 512 + k;
        float4 a = *(const float4*)src;
        float4 b = *(const float4*)(src + 4);
        f16x8 o = {(f16)a.x, (f16)a.y, (f16)a.z, (f16)a.w,
                   (f16)b.x, (f16)b.y, (f16)b.z, (f16)b.w};
        *(f16x8*)(Wfrag + (size_t)id * 8) = o;
    } else if (bid < 3840) {
        int id = (bid - 3584) * 256 + tid;  // R12-verified pack_watt4 body
        int j = id & 1023, k8 = id >> 10;
        const float* src = W_att + (size_t)j * 512 + k8 * 8;
        float4 a = *(const float4*)src;
        float4 b = *(const float4*)(src + 4);
        uint4 o = {pkh2(a.x, a.y), pkh2(a.z, a.w), pkh2(b.x, b.y),
                   pkh2(b.z, b.w)};
        wattQ[(size_t)k8 * 1024 + j] = o;
    } else if (bid < 4224) {
        int id = (bid - 3840) * 256 + tid;  // R12-verified pack_wcomb4 body
        int j = id & 511, k8 = id >> 9;
        const float* src = W_comb + (size_t)j * 1536 + k8 * 8;
        float4 a = *(const float4*)src;
        float4 b = *(const float4*)(src + 4);
        uint4 o = {pkh2(a.x, a.y), pkh2(a.z, a.w), pkh2(b.x, b.y),
                   pkh2(b.z, b.w)};
        wcombQ[(size_t)k8 * 512 + j] = o;
    } else if (bid < 5248) {
        int id = (bid - 4224) * 256 + tid;  // gather_x body
        int row = id >> 7;
        int e4 = (id & 127) * 4;
        int t = tok[row];
        float4 v = *(const float4*)(emb + (size_t)t * E + e4);
        f16x4 o = {(f16)v.x, (f16)v.y, (f16)v.z, (f16)v.w};
        ((f16x4*)x_h)[id] = o;
    } else {
        int i = (bid - 5248) * 256 + tid;   // init_h0 body
        int nn = i >> 8;
        int bb = (i >> 3) & 31;
        int ul = i & 7;
        xbuf[i] = (f16)h0[bb * 512 + nn * 8 + ul];
        if (i < NBLK) flags[i] = 0u;
    }
}

// ---------------- GEMM (proven): C = A @ W^T (+bias); PERM / MSWAP opts ----

template <bool BIAS, bool B2, bool PERM, bool MSWAP, typename OUT>
__global__ __launch_bounds__(256) void gemm_bt(
    const f16* __restrict__ A, int lda, const f16* __restrict__ W, int ldw,
    OUT* __restrict__ C, int ldc, int K, const float* __restrict__ bias1,
    const float* __restrict__ bias2) {
    __shared__ f16 smA[128 * 32];
    __shared__ f16 smB[128 * 32];
    const int tid = threadIdx.x;
    const int lane = tid & 63;
    const int wv = tid >> 6;
    const int wr = wv >> 1, wc = wv & 1;
    const int m0 = (MSWAP ? blockIdx.x : blockIdx.y) * 128;
    const int n0 = (MSWAP ? blockIdx.y : blockIdx.x) * 128;
    const int ar0 = tid >> 2;
    const int kq = (tid & 3) * 8;

    f32x4 acc[4][4];
#pragma unroll
    for (int m = 0; m < 4; m++)
#pragma unroll
        for (int n = 0; n < 4; n++) acc[m][n] = {0.f, 0.f, 0.f, 0.f};

    const int arow = wr * 64 + (lane & 15);
    const int brow = wc * 64 + (lane & 15);
    const int kk = (lane >> 4) * 8;

    const int ksteps = K >> 5;
    for (int s = 0; s < ksteps; ++s) {
        const int k0 = s * 32;
        const f16* Ag = A + (size_t)(m0 + ar0) * lda + k0 + kq;
        const f16* Wg = W + (size_t)(n0 + ar0) * ldw + k0 + kq;
#if HAVE_GLL
        __syncthreads();
        gll16(smA + wv * 512, Ag);
        gll16(smA + 2048 + wv * 512, Ag + (size_t)64 * lda);
        gll16(smB + wv * 512, Wg);
        gll16(smB + 2048 + wv * 512, Wg + (size_t)64 * ldw);
        __syncthreads();
#else
        uint4 va0 = *(const uint4*)Ag;
        uint4 va1 = *(const uint4*)(Ag + (size_t)64 * lda);
        uint4 vb0 = *(const uint4*)Wg;
        uint4 vb1 = *(const uint4*)(Wg + (size_t)64 * ldw);
        __syncthreads();
        *(uint4*)(smA + tid * 8) = va0;
        *(uint4*)(smA + (tid + 256) * 8) = va1;
        *(uint4*)(smB + tid * 8) = vb0;
        *(uint4*)(smB + (tid + 256) * 8) = vb1;
        __syncthreads();
#endif
        f16x8 af[4], bfr[4];
#pragma unroll
        for (int m = 0; m < 4; m++)
            af[m] = *(const f16x8*)(smA + (arow + m * 16) * 32 + kk);
#pragma unroll
        for (int n = 0; n < 4; n++)
            bfr[n] = *(const f16x8*)(smB + (brow + n * 16) * 32 + kk);
#pragma unroll
        for (int m = 0; m < 4; m++)
#pragma unroll
            for (int n = 0; n < 4; n++)
                acc[m][n] = __builtin_amdgcn_mfma_f32_16x16x32_f16(
                    af[m], bfr[n], acc[m][n], 0, 0, 0);
    }

    const int fr = lane & 15, fq = lane >> 4;
#pragma unroll
    for (int m = 0; m < 4; m++) {
        const int row0 = m0 + wr * 64 + m * 16 + fq * 4;
#pragma unroll
        for (int n = 0; n < 4; n++) {
            const int col = n0 + wc * 64 + n * 16 + fr;
            float bb = 0.f;
            if (BIAS) bb += bias1[col];
            if (B2) bb += bias2[col];
            int nb = 0, cl = 0;
            if (PERM) {
                int g = col >> 9;
                int unit = col & 511;
                nb = unit >> 3;
                cl = ((unit & 7) << 2) | g;
            }
#pragma unroll
            for (int r = 0; r < 4; r++) {
                float v = acc[m][n][r] + bb;
                if (PERM) {
                    int bt = row0 + r;
                    int b_ = bt >> 6, tt = bt & 63;
                    C[((size_t)(tt * 64 + nb) * 32 + b_) * 32 + cl] = (OUT)v;
                } else {
                    C[(size_t)(row0 + r) * ldc + col] = (OUT)v;
                }
            }
        }
    }
}

// ---------------- mega96c: scan (0-63) + CHUNKED feeders (64-95) -----------
// Scan: R14/R15-verified, byte-identical. hseq(t) valid when flags >= t+2;
//   epilogue publishes 66.
// Feeders (1/batch, R15-verified chunk code): per 8-step chunk g, wait
//   flags >= 8g+9, load 8 h vectors, amortize every weight/enc load over 8
//   timesteps (~18us/chunk < 32us scan cadence -> hidden), write outs
//   bt-major. L2-local traffic only (R14: no scan interference). One-way
//   dataflow -> deadlock-free regardless of residency. NO logits consumers
//   in-kernel (R13/R15 lesson: their MALL traffic inflates scan RTTs).

constexpr int LDS_BYTES = 43008;  // max(scan 37376, feeder 43008)

__global__ __launch_bounds__(256, 1) void mega96c(
    const float* __restrict__ gxp, const f16* __restrict__ Wfrag,
    const float* __restrict__ c0, f16* __restrict__ xbuf,
    unsigned* __restrict__ flags, f16* __restrict__ hseq,
    float* __restrict__ hout, float* __restrict__ cout,
    const uint4* __restrict__ wattQ, const f16* __restrict__ enc_h,
    const uint4* __restrict__ wcombQ, const float* __restrict__ b_comb,
    f16* __restrict__ outsP) {
    __shared__ __align__(16) char lds[LDS_BYTES];
    const int bid = blockIdx.x;
    const int tid = threadIdx.x;
    const int lane = tid & 63, wv = tid >> 6;

    if (bid < NBLK) {
        // ================= SCAN (R14-verified) =================
        const int n = bid;
        const int mi = wv >> 1, ni = wv & 1;
        f16(*hst)[520] = (f16(*)[520])lds;
        float(*gl)[32] = (float(*)[32])(lds + 33280);

        f16x8 bf[16];
        const f16* wbase =
            Wfrag + (size_t)((n * 2 + ni) * 16) * 512 + lane * 8;
#pragma unroll
        for (int ks = 0; ks < 16; ks++)
            bf[ks] = *(const f16x8*)(wbase + ks * 512);

        const int bb = tid >> 3, ul = tid & 7;
        const int unit = n * 8 + ul;
        float c = c0[bb * 512 + unit];
        float h = 0.f;

        const int sb = (tid & 63) >> 1;
        const int su0 = (tid & 1) * 4;
        const int arow = mi * 16 + (lane & 15);
        const int kcol0 = (lane >> 4) * 8;
        const int fr = lane & 15, fq = lane >> 4;

        for (int t = 0; t < T; ++t) {
            float4 gx4 = *(const float4*)(gxp +
                ((size_t)(t * NBLK + n) * 32 + bb) * 32 + ul * 4);
            for (;;) {
                unsigned v = ld_u32_cg(flags + lane);
                if (__all(v >= (unsigned)t)) break;
                __builtin_amdgcn_s_sleep(1);
            }
            asm volatile("" ::: "memory");
            const u64t* src = (const u64t*)(xbuf + (t & 1) * (B * H));
            u64t v[16];
#pragma unroll
            for (int i = 0; i < 16; i++) v[i] = ld_u64_cg(src + i * 256 + tid);
#pragma unroll
            for (int i = 0; i < 16; i++) {
                int np = i * 4 + wv;
                *(u64t*)(&hst[sb][np * 8 + su0]) = v[i];
            }
            __syncthreads();
            f32x4 acc0 = {0.f, 0.f, 0.f, 0.f}, acc1 = {0.f, 0.f, 0.f, 0.f};
#pragma unroll
            for (int ks = 0; ks < 16; ks++) {
                f16x8 af = *(const f16x8*)(&hst[arow][ks * 32 + kcol0]);
                if (ks & 1)
                    acc1 = __builtin_amdgcn_mfma_f32_16x16x32_f16(af, bf[ks],
                                                                  acc1, 0, 0, 0);
                else
                    acc0 = __builtin_amdgcn_mfma_f32_16x16x32_f16(af, bf[ks],
                                                                  acc0, 0, 0, 0);
            }
#pragma unroll
            for (int r = 0; r < 4; r++)
                gl[mi * 16 + fq * 4 + r][ni * 16 + fr] = acc0[r] + acc1[r];
            __syncthreads();
            float4 gv = *(const float4*)&gl[bb][ul * 4];
            float gi = gv.x + gx4.x;
            float gf = gv.y + gx4.y;
            float gg = gv.z + gx4.z;
            float go = gv.w + gx4.w;
            c = sigf(gf) * c + sigf(gi) * tanhf(gg);
            h = sigf(go) * tanhf(c);
            f16 hh = (f16)h;
            unsigned hv = (unsigned)__builtin_bit_cast(unsigned short, hh);
            unsigned other = (unsigned)__shfl_xor((int)hv, 1);
            unsigned packed = hv | (other << 16);
            f16* xn = xbuf + ((t + 1) & 1) * (B * H);
            if ((ul & 1) == 0)
                st_u32_cg((unsigned*)(xn + n * 256 + bb * 8 + ul), packed);
            if (t < T - 1) {
                asm volatile("s_waitcnt vmcnt(0)" ::: "memory");
                __syncthreads();
                if (tid == 0) st_u32_cg(flags + n, (unsigned)(t + 1));
            } else {
                __syncthreads();
            }
            if ((ul & 1) == 0)
                st_u32_cg((unsigned*)(hseq + ((size_t)t * 32 + bb) * 512 +
                                      unit), packed);
        }
        asm volatile("s_waitcnt vmcnt(0)" ::: "memory");
        __syncthreads();
        if (tid == 0) st_u32_cg(flags + n, 66u);
        hout[bb * 512 + unit] = h;
        cout[bb * 512 + unit] = c;

    } else {
        // ========== FEEDER (one batch b), 8-step chunks (R15-verified) =====
        const int b = bid - NBLK;
        unsigned(*hch)[256] = (unsigned(*)[256])lds;        // 8KB
        f16(*qch)[1024] = (f16(*)[1024])(lds + 8192);       // 16KB
        float(*wsch)[64] = (float(*)[64])(lds + 24576);     // 2KB
        f16(*apch)[1024] = (f16(*)[1024])(lds + 26624);     // 16KB
        const unsigned* hseqU = (const unsigned*)hseq;
        unsigned* outsU = (unsigned*)outsP;

        for (int g = 0; g < 8; ++g) {
            const unsigned target = (unsigned)(g * 8 + 9);
            for (;;) {
                unsigned v = ld_u32_cg(flags + lane);
                if (__all(v >= target)) break;
                __builtin_amdgcn_s_sleep(4);
            }
            asm volatile("" ::: "memory");
#pragma unroll
            for (int i = 0; i < 8; ++i)
                hch[i][tid] = ld_u32_cg(
                    hseqU + ((size_t)(g * 8 + i) * 32 + b) * 256 + tid);
            __syncthreads();
            // ---- q: 4 cols/thread x 8 t ----
            {
                float q0[8], q1[8], q2[8], q3[8];
#pragma unroll
                for (int i = 0; i < 8; ++i) {
                    q0[i] = 0.f; q1[i] = 0.f; q2[i] = 0.f; q3[i] = 0.f;
                }
                for (int k8 = 0; k8 < 64; ++k8) {
                    uint4 w0 = wattQ[(size_t)k8 * 1024 + tid];
                    uint4 w1 = wattQ[(size_t)k8 * 1024 + tid + 256];
                    uint4 w2 = wattQ[(size_t)k8 * 1024 + tid + 512];
                    uint4 w3 = wattQ[(size_t)k8 * 1024 + tid + 768];
#pragma unroll
                    for (int i = 0; i < 8; ++i) {
                        uint4 hh = *(const uint4*)&hch[i][k8 * 4];
                        q0[i] = dot2f(hh.x, w0.x, q0[i]);
                        q0[i] = dot2f(hh.y, w0.y, q0[i]);
                        q0[i] = dot2f(hh.z, w0.z, q0[i]);
                        q0[i] = dot2f(hh.w, w0.w, q0[i]);
                        q1[i] = dot2f(hh.x, w1.x, q1[i]);
                        q1[i] = dot2f(hh.y, w1.y, q1[i]);
                        q1[i] = dot2f(hh.z, w1.z, q1[i]);
                        q1[i] = dot2f(hh.w, w1.w, q1[i]);
                        q2[i] = dot2f(hh.x, w2.x, q2[i]);
                        q2[i] = dot2f(hh.y, w2.y, q2[i]);
                        q2[i] = dot2f(hh.z, w2.z, q2[i]);
                        q2[i] = dot2f(hh.w, w2.w, q2[i]);
                        q3[i] = dot2f(hh.x, w3.x, q3[i]);
                        q3[i] = dot2f(hh.y, w3.y, q3[i]);
                        q3[i] = dot2f(hh.z, w3.z, q3[i]);
                        q3[i] = dot2f(hh.w, w3.w, q3[i]);
                    }
                }
#pragma unroll
                for (int i = 0; i < 8; ++i) {
                    qch[i][tid] = (f16)q0[i];
                    qch[i][tid + 256] = (f16)q1[i];
                    qch[i][tid + 512] = (f16)q2[i];
                    qch[i][tid + 768] = (f16)q3[i];
                }
            }
            __syncthreads();
            // ---- w[s] = q . enc[b][s], 4 threads/s, 8 t ----
            {
                int s = tid >> 2, part = tid & 3;
                const unsigned* encp =
                    (const unsigned*)enc_h + ((size_t)(b * 64 + s)) * 512 +
                    part * 128;
                float wa[8];
#pragma unroll
                for (int i = 0; i < 8; ++i) wa[i] = 0.f;
                for (int it = 0; it < 32; ++it) {
                    uint4 e4 = *(const uint4*)&encp[it * 4];
#pragma unroll
                    for (int i = 0; i < 8; ++i) {
                        const unsigned* qp =
                            (const unsigned*)&qch[i][0] + part * 128;
                        uint4 q4 = *(const uint4*)&qp[it * 4];
                        wa[i] = dot2f(q4.x, e4.x, wa[i]);
                        wa[i] = dot2f(q4.y, e4.y, wa[i]);
                        wa[i] = dot2f(q4.z, e4.z, wa[i]);
                        wa[i] = dot2f(q4.w, e4.w, wa[i]);
                    }
                }
#pragma unroll
                for (int i = 0; i < 8; ++i) {
                    float w = wa[i];
                    w += __shfl_xor(w, 1);
                    w += __shfl_xor(w, 2);
                    if (part == 0) wsch[i][s] = w;
                }
            }
            __syncthreads();
            // ---- applied: 4 d/thread, 8 t ----
            {
                float a0[8], a1[8], a2[8], a3[8];
#pragma unroll
                for (int i = 0; i < 8; ++i) {
                    a0[i] = 0.f; a1[i] = 0.f; a2[i] = 0.f; a3[i] = 0.f;
                }
                for (int s2 = 0; s2 < 64; ++s2) {
                    const f16* er =
                        enc_h + ((size_t)(b * 64 + s2)) * 1024 + tid;
                    float e0 = (float)er[0];
                    float e1 = (float)er[256];
                    float e2 = (float)er[512];
                    float e3 = (float)er[768];
#pragma unroll
                    for (int i = 0; i < 8; ++i) {
                        float w = wsch[i][s2];
                        a0[i] += w * e0;
                        a1[i] += w * e1;
                        a2[i] += w * e2;
                        a3[i] += w * e3;
                    }
                }
#pragma unroll
                for (int i = 0; i < 8; ++i) {
                    apch[i][tid] = (f16)a0[i];
                    apch[i][tid + 256] = (f16)a1[i];
                    apch[i][tid + 512] = (f16)a2[i];
                    apch[i][tid + 768] = (f16)a3[i];
                }
            }
            __syncthreads();
            // ---- outs: 2 cols/thread x 8 t ----
            {
                float o0[8], o1[8];
#pragma unroll
                for (int i = 0; i < 8; ++i) { o0[i] = 0.f; o1[i] = 0.f; }
                for (int k8 = 0; k8 < 64; ++k8) {
                    uint4 w0 = wcombQ[(size_t)k8 * 512 + tid];
                    uint4 w1 = wcombQ[(size_t)k8 * 512 + tid + 256];
#pragma unroll
                    for (int i = 0; i < 8; ++i) {
                        uint4 hh = *(const uint4*)&hch[i][k8 * 4];
                        o0[i] = dot2f(hh.x, w0.x, o0[i]);
                        o0[i] = dot2f(hh.y, w0.y, o0[i]);
                        o0[i] = dot2f(hh.z, w0.z, o0[i]);
                        o0[i] = dot2f(hh.w, w0.w, o0[i]);
                        o1[i] = dot2f(hh.x, w1.x, o1[i]);
                        o1[i] = dot2f(hh.y, w1.y, o1[i]);
                        o1[i] = dot2f(hh.z, w1.z, o1[i]);
                        o1[i] = dot2f(hh.w, w1.w, o1[i]);
                    }
                }
                for (int k8 = 0; k8 < 128; ++k8) {
                    uint4 w0 = wcombQ[(size_t)(64 + k8) * 512 + tid];
                    uint4 w1 = wcombQ[(size_t)(64 + k8) * 512 + tid + 256];
#pragma unroll
                    for (int i = 0; i < 8; ++i) {
                        uint4 aa = *(const uint4*)((const unsigned*)&apch[i][0] +
                                                   k8 * 4);
                        o0[i] = dot2f(aa.x, w0.x, o0[i]);
                        o0[i] = dot2f(aa.y, w0.y, o0[i]);
                        o0[i] = dot2f(aa.z, w0.z, o0[i]);
                        o0[i] = dot2f(aa.w, w0.w, o0[i]);
                        o1[i] = dot2f(aa.x, w1.x, o1[i]);
                        o1[i] = dot2f(aa.y, w1.y, o1[i]);
                        o1[i] = dot2f(aa.z, w1.z, o1[i]);
                        o1[i] = dot2f(aa.w, w1.w, o1[i]);
                    }
                }
                float bc0 = b_comb[tid];
                float bc1 = b_comb[tid + 256];
#pragma unroll
                for (int i = 0; i < 8; ++i) {
                    float v0 = tanhf(o0[i] + bc0);
                    float v1 = tanhf(o1[i] + bc1);
                    unsigned p0 = (unsigned)__builtin_bit_cast(unsigned short,
                                                               (f16)v0);
                    unsigned p1 = (unsigned)__builtin_bit_cast(unsigned short,
                                                               (f16)v1);
                    unsigned s0 = (unsigned)__shfl_xor((int)p0, 1);
                    unsigned s1 = (unsigned)__shfl_xor((int)p1, 1);
                    if ((tid & 1) == 0) {
                        // bt-major: outs[(b*64 + 8g+i)][512] f16 = 256 u32
                        size_t base = ((size_t)(b * 64 + g * 8 + i)) * 256;
                        st_u32_cg(outsU + base + (tid >> 1), p0 | (s0 << 16));
                        st_u32_cg(outsU + base + 128 + (tid >> 1),
                                  p1 | (s1 << 16));
                    }
                }
            }
            __syncthreads();  // LDS reuse safety for next chunk
        }
        // outs stores flushed at kernel-boundary release
    }
}

// ---------------- launcher ----------------

extern "C" void kernel_launch(void* const* d_in, const int* in_sizes, int n_in,
                              void* d_out, int out_size, void* d_ws,
                              size_t ws_size, hipStream_t stream) {
    const int* tok = (const int*)d_in[0];
    const float* enc = (const float*)d_in[1];
    const float* h0 = (const float*)d_in[2];
    const float* c0 = (const float*)d_in[3];
    const float* emb = (const float*)d_in[4];
    const float* W_ih = (const float*)d_in[5];
    const float* W_hh = (const float*)d_in[6];
    const float* b_ih = (const float*)d_in[7];
    const float* b_hh = (const float*)d_in[8];
    const float* W_att = (const float*)d_in[9];
    const float* W_comb = (const float*)d_in[10];
    const float* b_comb = (const float*)d_in[11];
    const float* W_out = (const float*)d_in[12];
    const float* b_out = (const float*)d_in[13];

    float* out_logits = (float*)d_out;
    float* out_h = out_logits + (size_t)BT * V;
    float* out_c = out_h + (size_t)B * H;

    char* p = (char*)d_ws;
    auto alloc = [&](size_t bytes) -> void* {
        void* r = (void*)p;
        p += (bytes + 255) & ~(size_t)255;
        return r;
    };
    f16* W_ih_h = (f16*)alloc((size_t)G4 * E * 2);           // 2MB
    f16* Wfrag = (f16*)alloc((size_t)NBLK * 2 * 16 * 64 * 8 * 2);  // 2MB
    f16* W_out_h = (f16*)alloc((size_t)V * 512 * 2);         // 32MB
    f16* enc_h = (f16*)alloc((size_t)B * S * 1024 * 2);      // 4MB
    uint4* wattQ = (uint4*)alloc((size_t)64 * 1024 * 16);    // 1MB
    uint4* wcombQ = (uint4*)alloc((size_t)192 * 512 * 16);   // 1.5MB
    f16* x_h = (f16*)alloc((size_t)BT * E * 2);              // 2MB
    float* gxp = (float*)alloc((size_t)T * NBLK * 32 * 32 * 4);  // 16MB
    f16* hseq = (f16*)alloc((size_t)T * B * 512 * 2);        // 2MB
    f16* outsP = (f16*)alloc((size_t)BT * 512 * 2);          // 2MB (bt-major)
    f16* xbuf = (f16*)alloc((size_t)2 * B * H * 2);          // 128KB
    unsigned* flags = (unsigned*)alloc(256);

    // fused small preps (exact ranges) + big W_out cvt
    prep_all<<<5312, 256, 0, stream>>>(W_ih, W_ih_h, enc, enc_h, W_hh, Wfrag,
                                       W_att, wattQ, W_comb, wcombQ, tok, emb,
                                       x_h, h0, xbuf, flags);
    cvt_f16<<<2048, 256, 0, stream>>>(W_out, W_out_h, V * 512 / 4);

    // gates_x = x @ W_ih^T + b_ih + b_hh, permuted for the scan
    gemm_bt<true, true, true, false, float><<<dim3(16, 16), 256, 0, stream>>>(
        x_h, E, W_ih_h, E, gxp, 0, E, b_ih, b_hh);

    // fused scan + chunked attention feeders (hidden in scan's idle shadow)
    mega96c<<<NBLK + NFEED, 256, 0, stream>>>(gxp, Wfrag, c0, xbuf, flags,
                                              hseq, out_h, out_c, wattQ,
                                              enc_h, wcombQ, b_comb, outsP);

    // logits = outs @ W_out^T + b_out   [2048 x 32000] fp32 -> d_out
    // separate kernel (R13/R15 lesson); MSWAP for W-panel L2 reuse
    gemm_bt<true, false, false, true, float>
        <<<dim3(16, 250), 256, 0, stream>>>(outsP, 512, W_out_h, 512,
                                            out_logits, V, 512, b_out,
                                            nullptr);
}